// Round 1
// baseline (4194.580 us; speedup 1.0000x reference)
//
#include <hip/hip_runtime.h>
#include <hip/hip_bf16.h>
#include <math.h>

// Problem constants
#define BBv   4
#define TTv   2048
#define DMv   768
#define DIv   1536
#define NSv   64
#define DCv   4
#define RRv   48
#define PJW   176              // R + 2N
#define NLYR  2
#define MROWS (BBv * TTv)      // 8192

typedef __attribute__((ext_vector_type(8))) short short8;
typedef __attribute__((ext_vector_type(4))) float f32x4;

__device__ __forceinline__ __hip_bfloat16 f2bf(float f) { return __float2bfloat16(f); }
__device__ __forceinline__ float bf2f(__hip_bfloat16 h) { return __bfloat162float(h); }

// ---------------------------------------------------------------------------
// Weight conversion fp32 -> bf16 (all 4 weight tensors, both layers)
// ---------------------------------------------------------------------------
__global__ void cvt_weights_kernel(const float* __restrict__ w_in,
                                   const float* __restrict__ w_xp,
                                   const float* __restrict__ w_dt,
                                   const float* __restrict__ w_out,
                                   __hip_bfloat16* __restrict__ o_in,
                                   __hip_bfloat16* __restrict__ o_xp,
                                   __hip_bfloat16* __restrict__ o_dt,
                                   __hip_bfloat16* __restrict__ o_out)
{
    const size_t S1 = (size_t)NLYR * 2 * DIv * DMv;   // 4718592
    const size_t S2 = (size_t)NLYR * PJW * DIv;       // 540672
    const size_t S3 = (size_t)NLYR * DIv * RRv;       // 147456
    const size_t S4 = (size_t)NLYR * DMv * DIv;       // 2359296
    const size_t total = S1 + S2 + S3 + S4;
    for (size_t i = (size_t)blockIdx.x * blockDim.x + threadIdx.x; i < total;
         i += (size_t)gridDim.x * blockDim.x) {
        if (i < S1)                o_in[i]            = f2bf(w_in[i]);
        else if (i < S1 + S2)      o_xp[i - S1]       = f2bf(w_xp[i - S1]);
        else if (i < S1 + S2 + S3) o_dt[i - S1 - S2]  = f2bf(w_dt[i - S1 - S2]);
        else                       o_out[i - S1 - S2 - S3] = f2bf(w_out[i - S1 - S2 - S3]);
    }
}

// ---------------------------------------------------------------------------
// x_cur = x * mask (fp32) and x_bf = bf16(x_cur)
// ---------------------------------------------------------------------------
__global__ void mask_x_kernel(const float* __restrict__ x,
                              const float* __restrict__ mask,
                              float* __restrict__ x_cur,
                              __hip_bfloat16* __restrict__ x_bf)
{
    size_t idx = (size_t)blockIdx.x * 256 + threadIdx.x;
    if (idx >= (size_t)MROWS * DMv) return;
    size_t row = idx / DMv;
    float v = x[idx] * mask[row];
    x_cur[idx] = v;
    x_bf[idx] = f2bf(v);
}

// ---------------------------------------------------------------------------
// GEMM: C[m,n] = sum_k A[m,k] * B[n,k]   (A,B bf16; C fp32 or bf16)
// EPI: 0 = fp32 store, 1 = bf16 store, 2 = softplus(x + bias[n]) fp32 store
// Tiles: BM=BN=64, BK=32. 256 threads = 4 waves, each wave 32x32 (2x2 MFMAs).
// ---------------------------------------------------------------------------
template<int EPI>
__global__ __launch_bounds__(256)
void gemm_nt(const __hip_bfloat16* __restrict__ A, int lda,
             const __hip_bfloat16* __restrict__ Bw, int ldb,
             float* __restrict__ Cf, __hip_bfloat16* __restrict__ Ch, int ldc,
             const float* __restrict__ bias, int M, int N, int K)
{
    __shared__ __align__(16) __hip_bfloat16 sA[64 * 48];
    __shared__ __align__(16) __hip_bfloat16 sB[64 * 48];
    const int tid = threadIdx.x;
    const int m0 = blockIdx.y * 64;
    const int n0 = blockIdx.x * 64;
    const int w = tid >> 6, lane = tid & 63;
    const int wr = (w >> 1) << 5;   // 0 or 32 (row sub-tile)
    const int wc = (w & 1) << 5;    // 0 or 32 (col sub-tile)
    const int lr = lane & 15, lk = lane >> 4;
    const int srow = tid >> 2;          // 0..63
    const int scol = (tid & 3) << 3;    // 0,8,16,24
    f32x4 acc[2][2] = {};
    const bool bvalid = (n0 + srow) < N;

    for (int k0 = 0; k0 < K; k0 += 32) {
        uint4 av = {0u, 0u, 0u, 0u}, bv = {0u, 0u, 0u, 0u};
        const bool kv = (k0 + scol) < K;   // chunk-granular (K % 8 == 0 always)
        if (kv)
            av = *(const uint4*)(A + (size_t)(m0 + srow) * lda + (k0 + scol));
        if (kv && bvalid)
            bv = *(const uint4*)(Bw + (size_t)(n0 + srow) * ldb + (k0 + scol));
        *(uint4*)(sA + srow * 48 + scol) = av;
        *(uint4*)(sB + srow * 48 + scol) = bv;
        __syncthreads();
        short8 af0 = *(const short8*)(sA + (wr + lr) * 48 + (lk << 3));
        short8 af1 = *(const short8*)(sA + (wr + 16 + lr) * 48 + (lk << 3));
        short8 bf0 = *(const short8*)(sB + (wc + lr) * 48 + (lk << 3));
        short8 bf1 = *(const short8*)(sB + (wc + 16 + lr) * 48 + (lk << 3));
        acc[0][0] = __builtin_amdgcn_mfma_f32_16x16x32_bf16(af0, bf0, acc[0][0], 0, 0, 0);
        acc[0][1] = __builtin_amdgcn_mfma_f32_16x16x32_bf16(af0, bf1, acc[0][1], 0, 0, 0);
        acc[1][0] = __builtin_amdgcn_mfma_f32_16x16x32_bf16(af1, bf0, acc[1][0], 0, 0, 0);
        acc[1][1] = __builtin_amdgcn_mfma_f32_16x16x32_bf16(af1, bf1, acc[1][1], 0, 0, 0);
        __syncthreads();
    }
    // C/D layout (m89-verified): col = lane&15, row = (lane>>4)*4 + r
    #pragma unroll
    for (int i = 0; i < 2; ++i) {
        #pragma unroll
        for (int j = 0; j < 2; ++j) {
            const int col = n0 + wc + (j << 4) + lr;
            if (col >= N) continue;
            #pragma unroll
            for (int r = 0; r < 4; ++r) {
                const int row = m0 + wr + (i << 4) + (lk << 2) + r;
                float v = acc[i][j][r];
                const size_t ci = (size_t)row * ldc + col;
                if constexpr (EPI == 0) {
                    Cf[ci] = v;
                } else if constexpr (EPI == 1) {
                    Ch[ci] = f2bf(v);
                } else {
                    float xx = v + bias[col];
                    Cf[ci] = fmaxf(xx, 0.f) + log1pf(__expf(-fabsf(xx)));
                }
            }
        }
    }
}

// ---------------------------------------------------------------------------
// Causal depthwise conv (DC=4) + bias + SiLU. Reads u-half of xz (bf16).
// ---------------------------------------------------------------------------
__global__ void conv_silu_kernel(const __hip_bfloat16* __restrict__ xz,
                                 const float* __restrict__ Wc,   // [DI, DC]
                                 const float* __restrict__ bc,   // [DI]
                                 __hip_bfloat16* __restrict__ uc)
{
    size_t idx = (size_t)blockIdx.x * 256 + threadIdx.x;
    if (idx >= (size_t)MROWS * DIv) return;
    int d = (int)(idx % DIv);
    size_t row = idx / DIv;
    int t = (int)(row % TTv);
    float acc = bc[d];
    #pragma unroll
    for (int k = 0; k < DCv; ++k) {
        int tt = t - (DCv - 1) + k;
        if (tt >= 0)
            acc += Wc[d * DCv + k] *
                   bf2f(xz[(row - (DCv - 1) + k) * (2 * DIv) + d]);
    }
    float s = acc / (1.f + __expf(-acc));   // silu
    uc[idx] = f2bf(s);
}

// ---------------------------------------------------------------------------
// dt slice of proj -> bf16 (A operand of dt GEMM)
// ---------------------------------------------------------------------------
__global__ void cvt_dt_kernel(const float* __restrict__ proj,
                              __hip_bfloat16* __restrict__ dt_bf)
{
    size_t idx = (size_t)blockIdx.x * 256 + threadIdx.x;
    if (idx >= (size_t)MROWS * RRv) return;
    size_t m = idx / RRv;
    int r = (int)(idx % RRv);
    dt_bf[idx] = f2bf(proj[m * PJW + r]);
}

// ---------------------------------------------------------------------------
// Selective scan. One wave per (b,d); lane n holds h[n].
// Fuses: state recurrence, y = h.C, + u*D, * silu(z). Writes y as bf16.
// ---------------------------------------------------------------------------
__global__ __launch_bounds__(256)
void scan_kernel(const float* __restrict__ delta,          // [B*T, DI]
                 const __hip_bfloat16* __restrict__ uc,    // [B*T, DI]
                 const __hip_bfloat16* __restrict__ xz,    // [B*T, 2DI]; z at +DI
                 const float* __restrict__ proj,           // [B*T, PJW]
                 const float* __restrict__ a_log,          // [DI, N] (layer slice)
                 const float* __restrict__ Dp,             // [DI]   (layer slice)
                 __hip_bfloat16* __restrict__ y)           // [B*T, DI]
{
    const int w = threadIdx.x >> 6;
    const int lane = threadIdx.x & 63;
    int wid = blockIdx.x * 4 + w;
    const int b = __builtin_amdgcn_readfirstlane(wid / DIv);
    const int d = __builtin_amdgcn_readfirstlane(wid % DIv);

    // A2 = -exp(A_log) * log2(e), so exp(delta*A) == exp2(delta*A2)
    const float A2 = -__expf(a_log[d * NSv + lane]) * 1.44269504088896f;
    const float Dd = Dp[d];

    const float* dp = delta + (size_t)b * TTv * DIv + d;
    const __hip_bfloat16* up = uc + (size_t)b * TTv * DIv + d;
    const __hip_bfloat16* zp = xz + (size_t)b * TTv * (2 * DIv) + DIv + d;
    const float* pp = proj + (size_t)b * TTv * PJW + RRv + lane;
    __hip_bfloat16* yp = y + (size_t)b * TTv * DIv + d;

    float h = 0.f;
    for (int t = 0; t < TTv; ++t) {
        float dlt = dp[(size_t)t * DIv];                 // wave-uniform scalar
        float u   = bf2f(up[(size_t)t * DIv]);
        float z   = bf2f(zp[(size_t)t * (2 * DIv)]);
        float Bt  = pp[(size_t)t * PJW];                 // lane n -> B[t,n]
        float Ct  = pp[(size_t)t * PJW + NSv];           // lane n -> C[t,n]
        float e = exp2f(dlt * A2);
        h = h * e + (dlt * u) * Bt;
        float acc = h * Ct;
        #pragma unroll
        for (int off = 32; off > 0; off >>= 1)
            acc += __shfl_xor(acc, off, 64);
        float yv = acc + u * Dd;
        float sig = 1.f / (1.f + __expf(-z));
        yv *= z * sig;
        if (lane == 0) yp[(size_t)t * DIv] = f2bf(yv);
    }
}

// ---------------------------------------------------------------------------
// LayerNorm + FiLM + residual. One block per (b,t) row of 768.
// Writes fp32 result (x_cur or d_out) and bf16 copy for next layer's GEMM.
// ---------------------------------------------------------------------------
__global__ __launch_bounds__(256)
void ln_film_res_kernel(const float* __restrict__ h,       // [B*T, DM]
                        const float* __restrict__ xres,    // [B*T, DM]
                        const float* __restrict__ lw,      // [DM]
                        const float* __restrict__ lb,      // [DM]
                        const float* __restrict__ gamma,   // [B*T*DM] slice
                        const float* __restrict__ beta,    // [B*T*DM] slice
                        float* __restrict__ xout,
                        __hip_bfloat16* __restrict__ xbf)
{
    __shared__ float sm[4];
    const int row = blockIdx.x;
    const int tid = threadIdx.x;
    const int w = tid >> 6, lane = tid & 63;
    const float* hr = h + (size_t)row * DMv;
    float v0 = hr[tid], v1 = hr[tid + 256], v2 = hr[tid + 512];

    float s = v0 + v1 + v2;
    #pragma unroll
    for (int off = 32; off > 0; off >>= 1) s += __shfl_xor(s, off, 64);
    if (lane == 0) sm[w] = s;
    __syncthreads();
    float mean = (sm[0] + sm[1] + sm[2] + sm[3]) * (1.f / DMv);
    __syncthreads();

    float d0 = v0 - mean, d1 = v1 - mean, d2 = v2 - mean;
    float vs = d0 * d0 + d1 * d1 + d2 * d2;
    #pragma unroll
    for (int off = 32; off > 0; off >>= 1) vs += __shfl_xor(vs, off, 64);
    if (lane == 0) sm[w] = vs;
    __syncthreads();
    float var = (sm[0] + sm[1] + sm[2] + sm[3]) * (1.f / DMv);
    float rstd = rsqrtf(var + 1e-5f);

    const float dv[3] = {d0, d1, d2};
    #pragma unroll
    for (int e = 0; e < 3; ++e) {
        int c = tid + e * 256;
        size_t gi = (size_t)row * DMv + c;
        float ln = dv[e] * rstd * lw[c] + lb[c];
        float f = gamma[gi] * ln + beta[gi];
        float o = f + xres[gi];
        xout[gi] = o;
        xbf[gi] = f2bf(o);
    }
}

// ---------------------------------------------------------------------------
// Launch wrapper
// ---------------------------------------------------------------------------
extern "C" void kernel_launch(void* const* d_in, const int* in_sizes, int n_in,
                              void* d_out, int out_size, void* d_ws, size_t ws_size,
                              hipStream_t stream)
{
    const float* x     = (const float*)d_in[0];
    const float* mask  = (const float*)d_in[1];
    const float* fg    = (const float*)d_in[2];
    const float* fb    = (const float*)d_in[3];
    const float* w_in  = (const float*)d_in[4];
    const float* w_c   = (const float*)d_in[5];
    const float* b_c   = (const float*)d_in[6];
    const float* w_xp  = (const float*)d_in[7];
    const float* w_dt  = (const float*)d_in[8];
    const float* b_dt  = (const float*)d_in[9];
    const float* a_log = (const float*)d_in[10];
    const float* Dp    = (const float*)d_in[11];
    const float* w_out = (const float*)d_in[12];
    const float* ln_w  = (const float*)d_in[13];
    const float* ln_b  = (const float*)d_in[14];

    char* p = (char*)d_ws;
    __hip_bfloat16* xz_bf  = (__hip_bfloat16*)p; p += (size_t)MROWS * 2 * DIv * 2;  // 50.3 MB
    __hip_bfloat16* uc_bf  = (__hip_bfloat16*)p; p += (size_t)MROWS * DIv * 2;      // 25.2 MB
    __hip_bfloat16* y_bf   = (__hip_bfloat16*)p; p += (size_t)MROWS * DIv * 2;      // 25.2 MB
    __hip_bfloat16* x_bf   = (__hip_bfloat16*)p; p += (size_t)MROWS * DMv * 2;      // 12.6 MB
    __hip_bfloat16* dtA_bf = (__hip_bfloat16*)p; p += (size_t)MROWS * RRv * 2;      // 0.8 MB
    __hip_bfloat16* wbf_in = (__hip_bfloat16*)p; p += (size_t)NLYR * 2 * DIv * DMv * 2;
    __hip_bfloat16* wbf_xp = (__hip_bfloat16*)p; p += (size_t)NLYR * PJW * DIv * 2;
    __hip_bfloat16* wbf_dt = (__hip_bfloat16*)p; p += (size_t)NLYR * DIv * RRv * 2;
    __hip_bfloat16* wbf_out= (__hip_bfloat16*)p; p += (size_t)NLYR * DMv * DIv * 2;
    float* proj  = (float*)p; p += (size_t)MROWS * PJW * 4;                          // 5.8 MB
    float* delta = (float*)p; p += (size_t)MROWS * DIv * 4;                          // 50.3 MB
    float* x_cur = (float*)p; p += (size_t)MROWS * DMv * 4;                          // 25.2 MB
    float* hbuf  = delta;  // out_proj output aliases delta (dead after scan)

    cvt_weights_kernel<<<4096, 256, 0, stream>>>(w_in, w_xp, w_dt, w_out,
                                                 wbf_in, wbf_xp, wbf_dt, wbf_out);
    mask_x_kernel<<<(MROWS * DMv) / 256, 256, 0, stream>>>(x, mask, x_cur, x_bf);

    for (int L = 0; L < NLYR; ++L) {
        const __hip_bfloat16* WinL  = wbf_in  + (size_t)L * 2 * DIv * DMv;
        const __hip_bfloat16* WxpL  = wbf_xp  + (size_t)L * PJW * DIv;
        const __hip_bfloat16* WdtL  = wbf_dt  + (size_t)L * DIv * RRv;
        const __hip_bfloat16* WoutL = wbf_out + (size_t)L * DMv * DIv;

        // 1) xz = x @ W_in^T   (M=8192, N=3072, K=768) -> bf16
        gemm_nt<1><<<dim3(2 * DIv / 64, MROWS / 64), 256, 0, stream>>>(
            x_bf, DMv, WinL, DMv, nullptr, xz_bf, 2 * DIv, nullptr,
            MROWS, 2 * DIv, DMv);

        // 2) causal depthwise conv + silu
        conv_silu_kernel<<<(MROWS * DIv) / 256, 256, 0, stream>>>(
            xz_bf, w_c + (size_t)L * DIv * DCv, b_c + (size_t)L * DIv, uc_bf);

        // 3) proj = u_c @ W_x^T  (M=8192, N=176, K=1536) -> fp32
        gemm_nt<0><<<dim3((PJW + 63) / 64, MROWS / 64), 256, 0, stream>>>(
            uc_bf, DIv, WxpL, DIv, proj, nullptr, PJW, nullptr,
            MROWS, PJW, DIv);

        // 4) dt slice -> bf16
        cvt_dt_kernel<<<(MROWS * RRv) / 256, 256, 0, stream>>>(proj, dtA_bf);

        // 5) delta = softplus(dt @ W_dt^T + b_dt)  (M=8192, N=1536, K=48)
        gemm_nt<2><<<dim3(DIv / 64, MROWS / 64), 256, 0, stream>>>(
            dtA_bf, RRv, WdtL, RRv, delta, nullptr, DIv,
            b_dt + (size_t)L * DIv, MROWS, DIv, RRv);

        // 6) selective scan -> y (bf16)
        scan_kernel<<<(BBv * DIv) / 4, 256, 0, stream>>>(
            delta, uc_bf, xz_bf, proj,
            a_log + (size_t)L * DIv * NSv, Dp + (size_t)L * DIv, y_bf);

        // 7) h = y @ W_out^T  (M=8192, N=768, K=1536) -> fp32 (aliases delta)
        gemm_nt<0><<<dim3(DMv / 64, MROWS / 64), 256, 0, stream>>>(
            y_bf, DIv, WoutL, DIv, hbuf, nullptr, DMv, nullptr,
            MROWS, DMv, DIv);

        // 8) LN + FiLM + residual
        float* xo = (L == NLYR - 1) ? (float*)d_out : x_cur;
        ln_film_res_kernel<<<MROWS, 256, 0, stream>>>(
            hbuf, x_cur, ln_w + (size_t)L * DMv, ln_b + (size_t)L * DMv,
            fg + (size_t)L * MROWS * DMv, fb + (size_t)L * MROWS * DMv,
            xo, x_bf);
    }
}

// Round 2
// 1920.334 us; speedup vs baseline: 2.1843x; 2.1843x over previous
//
#include <hip/hip_runtime.h>
#include <hip/hip_bf16.h>
#include <math.h>

// Problem constants
#define BBv   4
#define TTv   2048
#define DMv   768
#define DIv   1536
#define NSv   64
#define DCv   4
#define RRv   48
#define PJW   176              // R + 2N
#define NLYR  2
#define MROWS (BBv * TTv)      // 8192

// Scan tiling
#define TBLK  32               // t-steps per LDS flush
#define LDST  68               // LDS row stride (floats): 64 + 4 pad, 16B-aligned

typedef __attribute__((ext_vector_type(8))) short short8;
typedef __attribute__((ext_vector_type(4))) float f32x4;

__device__ __forceinline__ __hip_bfloat16 f2bf(float f) { return __float2bfloat16(f); }
__device__ __forceinline__ float bf2f(__hip_bfloat16 h) { return __bfloat162float(h); }

// ---------------------------------------------------------------------------
// Weight conversion fp32 -> bf16 (all 4 weight tensors, both layers)
// ---------------------------------------------------------------------------
__global__ void cvt_weights_kernel(const float* __restrict__ w_in,
                                   const float* __restrict__ w_xp,
                                   const float* __restrict__ w_dt,
                                   const float* __restrict__ w_out,
                                   __hip_bfloat16* __restrict__ o_in,
                                   __hip_bfloat16* __restrict__ o_xp,
                                   __hip_bfloat16* __restrict__ o_dt,
                                   __hip_bfloat16* __restrict__ o_out)
{
    const size_t S1 = (size_t)NLYR * 2 * DIv * DMv;
    const size_t S2 = (size_t)NLYR * PJW * DIv;
    const size_t S3 = (size_t)NLYR * DIv * RRv;
    const size_t S4 = (size_t)NLYR * DMv * DIv;
    const size_t total = S1 + S2 + S3 + S4;
    for (size_t i = (size_t)blockIdx.x * blockDim.x + threadIdx.x; i < total;
         i += (size_t)gridDim.x * blockDim.x) {
        if (i < S1)                o_in[i]            = f2bf(w_in[i]);
        else if (i < S1 + S2)      o_xp[i - S1]       = f2bf(w_xp[i - S1]);
        else if (i < S1 + S2 + S3) o_dt[i - S1 - S2]  = f2bf(w_dt[i - S1 - S2]);
        else                       o_out[i - S1 - S2 - S3] = f2bf(w_out[i - S1 - S2 - S3]);
    }
}

// ---------------------------------------------------------------------------
// x_cur = x * mask (fp32) and x_bf = bf16(x_cur)
// ---------------------------------------------------------------------------
__global__ void mask_x_kernel(const float* __restrict__ x,
                              const float* __restrict__ mask,
                              float* __restrict__ x_cur,
                              __hip_bfloat16* __restrict__ x_bf)
{
    size_t idx = (size_t)blockIdx.x * 256 + threadIdx.x;
    if (idx >= (size_t)MROWS * DMv) return;
    size_t row = idx / DMv;
    float v = x[idx] * mask[row];
    x_cur[idx] = v;
    x_bf[idx] = f2bf(v);
}

// ---------------------------------------------------------------------------
// GEMM: C[m,n] = sum_k A[m,k] * B[n,k]   (A,B bf16)
// EPI: 0 = fp32 store, 1 = bf16 store, 2 = softplus(x + bias[n]) fp32 store,
//      3 = x_proj split: col<48 -> bf16 dt (Ch, ld 48);
//          col 48..111 -> BC[row*128 + 2*(col-48)]   (B, fp32)
//          col 112..175-> BC[row*128 + 2*(col-112)+1] (C, fp32)
// Tiles: BM=BN=64, BK=32. 256 threads = 4 waves, each wave 32x32 (2x2 MFMAs).
// ---------------------------------------------------------------------------
template<int EPI>
__global__ __launch_bounds__(256)
void gemm_nt(const __hip_bfloat16* __restrict__ A, int lda,
             const __hip_bfloat16* __restrict__ Bw, int ldb,
             float* __restrict__ Cf, __hip_bfloat16* __restrict__ Ch, int ldc,
             const float* __restrict__ bias, int M, int N, int K)
{
    __shared__ __align__(16) __hip_bfloat16 sA[64 * 48];
    __shared__ __align__(16) __hip_bfloat16 sB[64 * 48];
    const int tid = threadIdx.x;
    const int m0 = blockIdx.y * 64;
    const int n0 = blockIdx.x * 64;
    const int w = tid >> 6, lane = tid & 63;
    const int wr = (w >> 1) << 5;
    const int wc = (w & 1) << 5;
    const int lr = lane & 15, lk = lane >> 4;
    const int srow = tid >> 2;
    const int scol = (tid & 3) << 3;
    f32x4 acc[2][2] = {};
    const bool bvalid = (n0 + srow) < N;

    for (int k0 = 0; k0 < K; k0 += 32) {
        uint4 av = {0u, 0u, 0u, 0u}, bv = {0u, 0u, 0u, 0u};
        const bool kv = (k0 + scol) < K;
        if (kv)
            av = *(const uint4*)(A + (size_t)(m0 + srow) * lda + (k0 + scol));
        if (kv && bvalid)
            bv = *(const uint4*)(Bw + (size_t)(n0 + srow) * ldb + (k0 + scol));
        *(uint4*)(sA + srow * 48 + scol) = av;
        *(uint4*)(sB + srow * 48 + scol) = bv;
        __syncthreads();
        short8 af0 = *(const short8*)(sA + (wr + lr) * 48 + (lk << 3));
        short8 af1 = *(const short8*)(sA + (wr + 16 + lr) * 48 + (lk << 3));
        short8 bf0 = *(const short8*)(sB + (wc + lr) * 48 + (lk << 3));
        short8 bf1 = *(const short8*)(sB + (wc + 16 + lr) * 48 + (lk << 3));
        acc[0][0] = __builtin_amdgcn_mfma_f32_16x16x32_bf16(af0, bf0, acc[0][0], 0, 0, 0);
        acc[0][1] = __builtin_amdgcn_mfma_f32_16x16x32_bf16(af0, bf1, acc[0][1], 0, 0, 0);
        acc[1][0] = __builtin_amdgcn_mfma_f32_16x16x32_bf16(af1, bf0, acc[1][0], 0, 0, 0);
        acc[1][1] = __builtin_amdgcn_mfma_f32_16x16x32_bf16(af1, bf1, acc[1][1], 0, 0, 0);
        __syncthreads();
    }
    #pragma unroll
    for (int i = 0; i < 2; ++i) {
        #pragma unroll
        for (int j = 0; j < 2; ++j) {
            const int col = n0 + wc + (j << 4) + lr;
            if (col >= N) continue;
            #pragma unroll
            for (int r = 0; r < 4; ++r) {
                const int row = m0 + wr + (i << 4) + (lk << 2) + r;
                float v = acc[i][j][r];
                if constexpr (EPI == 0) {
                    Cf[(size_t)row * ldc + col] = v;
                } else if constexpr (EPI == 1) {
                    Ch[(size_t)row * ldc + col] = f2bf(v);
                } else if constexpr (EPI == 2) {
                    float xx = v + bias[col];
                    Cf[(size_t)row * ldc + col] =
                        fmaxf(xx, 0.f) + log1pf(__expf(-fabsf(xx)));
                } else {
                    if (col < RRv)
                        Ch[(size_t)row * RRv + col] = f2bf(v);
                    else if (col < RRv + NSv)
                        Cf[(size_t)row * 128 + 2 * (col - RRv)] = v;
                    else
                        Cf[(size_t)row * 128 + 2 * (col - RRv - NSv) + 1] = v;
                }
            }
        }
    }
}

// ---------------------------------------------------------------------------
// Causal depthwise conv (DC=4) + bias + SiLU. Reads u-half of xz (bf16).
// ---------------------------------------------------------------------------
__global__ void conv_silu_kernel(const __hip_bfloat16* __restrict__ xz,
                                 const float* __restrict__ Wc,
                                 const float* __restrict__ bc,
                                 __hip_bfloat16* __restrict__ uc)
{
    size_t idx = (size_t)blockIdx.x * 256 + threadIdx.x;
    if (idx >= (size_t)MROWS * DIv) return;
    int d = (int)(idx % DIv);
    size_t row = idx / DIv;
    int t = (int)(row % TTv);
    float acc = bc[d];
    #pragma unroll
    for (int k = 0; k < DCv; ++k) {
        int tt = t - (DCv - 1) + k;
        if (tt >= 0)
            acc += Wc[d * DCv + k] *
                   bf2f(xz[(row - (DCv - 1) + k) * (2 * DIv) + d]);
    }
    float s = acc / (1.f + __expf(-acc));
    uc[idx] = f2bf(s);
}

// ---------------------------------------------------------------------------
// Selective scan v2. One wave per (b,d); lane n holds h[n].
// Per-t path: only h = fma(h, e, du*B) is loop-carried; partials h*C go to a
// private LDS slice; every 32 t a transposed reduce + fused epilogue runs.
// B/C come interleaved from BC[t][2n],[2n+1] (one coalesced float2 per lane).
// Chunked (8 t) double-buffered register prefetch; NO __syncthreads anywhere.
// ---------------------------------------------------------------------------
__global__ __launch_bounds__(256, 4)
void scan_kernel(const float* __restrict__ delta,          // [B*T, DI]
                 const __hip_bfloat16* __restrict__ uc,    // [B*T, DI]
                 const __hip_bfloat16* __restrict__ xz,    // [B*T, 2DI]; z at +DI
                 const float* __restrict__ BC,             // [B*T, 128] interleaved
                 const float* __restrict__ a_log,          // [DI, N] layer slice
                 const float* __restrict__ Dp,             // [DI] layer slice
                 __hip_bfloat16* __restrict__ y)           // [B*T, DI]
{
    __shared__ __align__(16) float vbuf[4 * TBLK * LDST];  // 34816 B
    const int w = threadIdx.x >> 6;
    const int lane = threadIdx.x & 63;
    const int wid = blockIdx.x * 4 + w;
    const int b = __builtin_amdgcn_readfirstlane(wid / DIv);
    const int d = __builtin_amdgcn_readfirstlane(wid % DIv);
    const size_t bT = (size_t)b * TTv;

    // A2 = -exp(A_log)*log2(e): exp(delta*A) == exp2(delta*A2)
    const float A2 = -__expf(a_log[(size_t)d * NSv + lane]) * 1.44269504088896f;
    const float Dd = Dp[d];

    const float* dp = delta + bT * DIv + d;                // wave-uniform base
    const __hip_bfloat16* up = uc + bT * DIv + d;
    const float* bcp = BC + bT * 128 + 2 * lane;
    float* vb = vbuf + w * (TBLK * LDST);

    float2 bc[2][8];
    float  dl[2][8];
    float  uu[2][8];

    // preload chunk 0
    #pragma unroll
    for (int i = 0; i < 8; ++i) {
        bc[0][i] = *(const float2*)(bcp + (size_t)i * 128);
        dl[0][i] = dp[(size_t)i * DIv];
        uu[0][i] = bf2f(up[(size_t)i * DIv]);
    }

    float h = 0.f;
    for (int t0 = 0; t0 < TTv; t0 += TBLK) {
        #pragma unroll
        for (int q = 0; q < 4; ++q) {
            const int cur = q & 1, nxt = cur ^ 1;
            const int tn = t0 + q * 8 + 8;                 // next chunk base
            if (tn < TTv) {
                #pragma unroll
                for (int i = 0; i < 8; ++i) {
                    bc[nxt][i] = *(const float2*)(bcp + (size_t)(tn + i) * 128);
                    dl[nxt][i] = dp[(size_t)(tn + i) * DIv];
                    uu[nxt][i] = bf2f(up[(size_t)(tn + i) * DIv]);
                }
            }
            #pragma unroll
            for (int i = 0; i < 8; ++i) {
                const float dlt = dl[cur][i];
                const float e  = exp2f(dlt * A2);
                const float du = dlt * uu[cur][i];
                h = fmaf(h, e, du * bc[cur][i].x);         // the only carried dep
                vb[(q * 8 + i) * LDST + lane] = h * bc[cur][i].y;
            }
        }
        __asm__ volatile("s_waitcnt lgkmcnt(0)" ::: "memory");
        // transposed reduce: lane pair (r, r+32) sums row r's 64 partials
        const int r = lane & 31;
        const int cbase = (lane >> 5) << 5;
        const float* vr = vb + r * LDST + cbase;
        f32x4 a = *(const f32x4*)(vr);
        #pragma unroll
        for (int k = 1; k < 8; ++k)
            a += *(const f32x4*)(vr + 4 * k);
        float s = a[0] + a[1] + a[2] + a[3];
        s += __shfl_xor(s, 32, 64);
        if (lane < 32) {
            const size_t rowg = bT + t0 + r;
            const float u = bf2f(uc[rowg * DIv + d]);
            const float z = bf2f(xz[rowg * 2 * DIv + DIv + d]);
            float yv = s + u * Dd;
            yv *= z / (1.f + __expf(-z));                  // * silu(z)
            y[rowg * DIv + d] = f2bf(yv);
        }
    }
}

// ---------------------------------------------------------------------------
// LayerNorm + FiLM + residual. One block per (b,t) row of 768.
// ---------------------------------------------------------------------------
__global__ __launch_bounds__(256)
void ln_film_res_kernel(const float* __restrict__ h,
                        const float* __restrict__ xres,
                        const float* __restrict__ lw,
                        const float* __restrict__ lb,
                        const float* __restrict__ gamma,
                        const float* __restrict__ beta,
                        float* __restrict__ xout,
                        __hip_bfloat16* __restrict__ xbf)
{
    __shared__ float sm[4];
    const int row = blockIdx.x;
    const int tid = threadIdx.x;
    const int w = tid >> 6, lane = tid & 63;
    const float* hr = h + (size_t)row * DMv;
    float v0 = hr[tid], v1 = hr[tid + 256], v2 = hr[tid + 512];

    float s = v0 + v1 + v2;
    #pragma unroll
    for (int off = 32; off > 0; off >>= 1) s += __shfl_xor(s, off, 64);
    if (lane == 0) sm[w] = s;
    __syncthreads();
    float mean = (sm[0] + sm[1] + sm[2] + sm[3]) * (1.f / DMv);
    __syncthreads();

    float d0 = v0 - mean, d1 = v1 - mean, d2 = v2 - mean;
    float vs = d0 * d0 + d1 * d1 + d2 * d2;
    #pragma unroll
    for (int off = 32; off > 0; off >>= 1) vs += __shfl_xor(vs, off, 64);
    if (lane == 0) sm[w] = vs;
    __syncthreads();
    float var = (sm[0] + sm[1] + sm[2] + sm[3]) * (1.f / DMv);
    float rstd = rsqrtf(var + 1e-5f);

    const float dv[3] = {d0, d1, d2};
    #pragma unroll
    for (int e = 0; e < 3; ++e) {
        int c = tid + e * 256;
        size_t gi = (size_t)row * DMv + c;
        float ln = dv[e] * rstd * lw[c] + lb[c];
        float f = gamma[gi] * ln + beta[gi];
        float o = f + xres[gi];
        xout[gi] = o;
        xbf[gi] = f2bf(o);
    }
}

// ---------------------------------------------------------------------------
// Launch wrapper
// ---------------------------------------------------------------------------
extern "C" void kernel_launch(void* const* d_in, const int* in_sizes, int n_in,
                              void* d_out, int out_size, void* d_ws, size_t ws_size,
                              hipStream_t stream)
{
    const float* x     = (const float*)d_in[0];
    const float* mask  = (const float*)d_in[1];
    const float* fg    = (const float*)d_in[2];
    const float* fb    = (const float*)d_in[3];
    const float* w_in  = (const float*)d_in[4];
    const float* w_c   = (const float*)d_in[5];
    const float* b_c   = (const float*)d_in[6];
    const float* w_xp  = (const float*)d_in[7];
    const float* w_dt  = (const float*)d_in[8];
    const float* b_dt  = (const float*)d_in[9];
    const float* a_log = (const float*)d_in[10];
    const float* Dp    = (const float*)d_in[11];
    const float* w_out = (const float*)d_in[12];
    const float* ln_w  = (const float*)d_in[13];
    const float* ln_b  = (const float*)d_in[14];

    char* p = (char*)d_ws;
    __hip_bfloat16* xz_bf  = (__hip_bfloat16*)p; p += (size_t)MROWS * 2 * DIv * 2;
    __hip_bfloat16* uc_bf  = (__hip_bfloat16*)p; p += (size_t)MROWS * DIv * 2;
    __hip_bfloat16* y_bf   = (__hip_bfloat16*)p; p += (size_t)MROWS * DIv * 2;
    __hip_bfloat16* x_bf   = (__hip_bfloat16*)p; p += (size_t)MROWS * DMv * 2;
    __hip_bfloat16* dtA_bf = (__hip_bfloat16*)p; p += (size_t)MROWS * RRv * 2;
    __hip_bfloat16* wbf_in = (__hip_bfloat16*)p; p += (size_t)NLYR * 2 * DIv * DMv * 2;
    __hip_bfloat16* wbf_xp = (__hip_bfloat16*)p; p += (size_t)NLYR * PJW * DIv * 2;
    __hip_bfloat16* wbf_dt = (__hip_bfloat16*)p; p += (size_t)NLYR * DIv * RRv * 2;
    __hip_bfloat16* wbf_out= (__hip_bfloat16*)p; p += (size_t)NLYR * DMv * DIv * 2;
    float* BCbuf = (float*)p; p += (size_t)MROWS * 128 * 4;                 // 4.2 MB
    float* delta = (float*)p; p += (size_t)MROWS * DIv * 4;                 // 50.3 MB
    float* x_cur = (float*)p; p += (size_t)MROWS * DMv * 4;                 // 25.2 MB
    float* hbuf  = delta;  // out_proj output aliases delta (dead after scan)

    cvt_weights_kernel<<<4096, 256, 0, stream>>>(w_in, w_xp, w_dt, w_out,
                                                 wbf_in, wbf_xp, wbf_dt, wbf_out);
    mask_x_kernel<<<(MROWS * DMv) / 256, 256, 0, stream>>>(x, mask, x_cur, x_bf);

    for (int L = 0; L < NLYR; ++L) {
        const __hip_bfloat16* WinL  = wbf_in  + (size_t)L * 2 * DIv * DMv;
        const __hip_bfloat16* WxpL  = wbf_xp  + (size_t)L * PJW * DIv;
        const __hip_bfloat16* WdtL  = wbf_dt  + (size_t)L * DIv * RRv;
        const __hip_bfloat16* WoutL = wbf_out + (size_t)L * DMv * DIv;

        // 1) xz = x @ W_in^T   (M=8192, N=3072, K=768) -> bf16
        gemm_nt<1><<<dim3(2 * DIv / 64, MROWS / 64), 256, 0, stream>>>(
            x_bf, DMv, WinL, DMv, nullptr, xz_bf, 2 * DIv, nullptr,
            MROWS, 2 * DIv, DMv);

        // 2) causal depthwise conv + silu
        conv_silu_kernel<<<(MROWS * DIv) / 256, 256, 0, stream>>>(
            xz_bf, w_c + (size_t)L * DIv * DCv, b_c + (size_t)L * DIv, uc_bf);

        // 3) x_proj: dt->bf16 + BC interleaved  (M=8192, N=176, K=1536)
        gemm_nt<3><<<dim3((PJW + 63) / 64, MROWS / 64), 256, 0, stream>>>(
            uc_bf, DIv, WxpL, DIv, BCbuf, dtA_bf, 0, nullptr,
            MROWS, PJW, DIv);

        // 4) delta = softplus(dt @ W_dt^T + b_dt)  (M=8192, N=1536, K=48)
        gemm_nt<2><<<dim3(DIv / 64, MROWS / 64), 256, 0, stream>>>(
            dtA_bf, RRv, WdtL, RRv, delta, nullptr, DIv,
            b_dt + (size_t)L * DIv, MROWS, DIv, RRv);

        // 5) selective scan -> y (bf16)
        scan_kernel<<<(BBv * DIv) / 4, 256, 0, stream>>>(
            delta, uc_bf, xz_bf, BCbuf,
            a_log + (size_t)L * DIv * NSv, Dp + (size_t)L * DIv, y_bf);

        // 6) h = y @ W_out^T  (M=8192, N=768, K=1536) -> fp32 (aliases delta)
        gemm_nt<0><<<dim3(DMv / 64, MROWS / 64), 256, 0, stream>>>(
            y_bf, DIv, WoutL, DIv, hbuf, nullptr, DMv, nullptr,
            MROWS, DMv, DIv);

        // 7) LN + FiLM + residual
        float* xo = (L == NLYR - 1) ? (float*)d_out : x_cur;
        ln_film_res_kernel<<<MROWS, 256, 0, stream>>>(
            hbuf, x_cur, ln_w + (size_t)L * DMv, ln_b + (size_t)L * DMv,
            fg + (size_t)L * MROWS * DMv, fb + (size_t)L * MROWS * DMv,
            xo, x_bf);
    }
}

// Round 3
// 1660.123 us; speedup vs baseline: 2.5267x; 1.1567x over previous
//
#include <hip/hip_runtime.h>
#include <hip/hip_bf16.h>
#include <math.h>

// Problem constants
#define BBv   4
#define TTv   2048
#define DMv   768
#define DIv   1536
#define NSv   64
#define DCv   4
#define RRv   48
#define PJW   176              // R + 2N
#define NLYR  2
#define MROWS (BBv * TTv)      // 8192

// Scan tiling
#define TBLK  16               // t-steps per LDS flush
#define LDST  68               // LDS row stride (floats): quad-stride 17 (odd)

typedef __attribute__((ext_vector_type(8))) short short8;
typedef __attribute__((ext_vector_type(4))) float f32x4;

__device__ __forceinline__ __hip_bfloat16 f2bf(float f) { return __float2bfloat16(f); }
__device__ __forceinline__ float bf2f(__hip_bfloat16 h) { return __bfloat162float(h); }

// ---------------------------------------------------------------------------
// Weight conversion fp32 -> bf16
// ---------------------------------------------------------------------------
__global__ void cvt_weights_kernel(const float* __restrict__ w_in,
                                   const float* __restrict__ w_xp,
                                   const float* __restrict__ w_dt,
                                   const float* __restrict__ w_out,
                                   __hip_bfloat16* __restrict__ o_in,
                                   __hip_bfloat16* __restrict__ o_xp,
                                   __hip_bfloat16* __restrict__ o_dt,
                                   __hip_bfloat16* __restrict__ o_out)
{
    const size_t S1 = (size_t)NLYR * 2 * DIv * DMv;
    const size_t S2 = (size_t)NLYR * PJW * DIv;
    const size_t S3 = (size_t)NLYR * DIv * RRv;
    const size_t S4 = (size_t)NLYR * DMv * DIv;
    const size_t total = S1 + S2 + S3 + S4;
    for (size_t i = (size_t)blockIdx.x * blockDim.x + threadIdx.x; i < total;
         i += (size_t)gridDim.x * blockDim.x) {
        if (i < S1)                o_in[i]            = f2bf(w_in[i]);
        else if (i < S1 + S2)      o_xp[i - S1]       = f2bf(w_xp[i - S1]);
        else if (i < S1 + S2 + S3) o_dt[i - S1 - S2]  = f2bf(w_dt[i - S1 - S2]);
        else                       o_out[i - S1 - S2 - S3] = f2bf(w_out[i - S1 - S2 - S3]);
    }
}

// ---------------------------------------------------------------------------
// x_cur = x * mask (fp32) and x_bf = bf16(x_cur)
// ---------------------------------------------------------------------------
__global__ void mask_x_kernel(const float* __restrict__ x,
                              const float* __restrict__ mask,
                              float* __restrict__ x_cur,
                              __hip_bfloat16* __restrict__ x_bf)
{
    size_t idx = (size_t)blockIdx.x * 256 + threadIdx.x;
    if (idx >= (size_t)MROWS * DMv) return;
    size_t row = idx / DMv;
    float v = x[idx] * mask[row];
    x_cur[idx] = v;
    x_bf[idx] = f2bf(v);
}

// ---------------------------------------------------------------------------
// bf16 transpose: in [R, C] -> out [C, R]. 64x64 tiles, 256 threads.
// ---------------------------------------------------------------------------
__global__ __launch_bounds__(256)
void transpose_bf16(const ushort* __restrict__ in, ushort* __restrict__ out,
                    int R, int C)
{
    __shared__ ushort s[64][68];
    const int tx = threadIdx.x & 15;
    const int ty = threadIdx.x >> 4;
    const size_t r0 = (size_t)blockIdx.y * 64;
    const size_t c0 = (size_t)blockIdx.x * 64;
    #pragma unroll
    for (int i = 0; i < 4; ++i) {
        int r = ty + 16 * i;
        ushort4 v = *(const ushort4*)(in + (r0 + r) * C + c0 + tx * 4);
        *(ushort4*)&s[r][tx * 4] = v;
    }
    __syncthreads();
    #pragma unroll
    for (int i = 0; i < 4; ++i) {
        int c = ty + 16 * i;
        ushort4 v;
        v.x = s[tx * 4 + 0][c];
        v.y = s[tx * 4 + 1][c];
        v.z = s[tx * 4 + 2][c];
        v.w = s[tx * 4 + 3][c];
        *(ushort4*)(out + (c0 + c) * R + r0 + tx * 4) = v;
    }
}

// ---------------------------------------------------------------------------
// GEMM: C[m,n] = sum_k A[m,k] * B[n,k]   (A,B bf16)
// EPI 0: fp32 store to Cf[row*ldc+col]
// EPI 2: softplus(x + bias[col]) -> TRANSPOSED fp32 store Cf[col*MROWS+row] (f32x4)
// EPI 3: x_proj split: col<48 -> bf16 dt Ch[row*48+col];
//        col 48..111  -> Cf[row*128 + 2*(col-48)]    (B)
//        col 112..175 -> Cf[row*128 + 2*(col-112)+1] (C)
// EPI 4: in_proj split: col<DI -> bf16 u Ch[row*DI+col];
//        col>=DI -> TRANSPOSED bf16 z ChT[(col-DI)*MROWS+row] (ushort4)
// ---------------------------------------------------------------------------
template<int EPI>
__global__ __launch_bounds__(256)
void gemm_nt(const __hip_bfloat16* __restrict__ A, int lda,
             const __hip_bfloat16* __restrict__ Bw, int ldb,
             float* __restrict__ Cf, __hip_bfloat16* __restrict__ Ch,
             __hip_bfloat16* __restrict__ ChT, int ldc,
             const float* __restrict__ bias, int M, int N, int K)
{
    __shared__ __align__(16) __hip_bfloat16 sA[64 * 48];
    __shared__ __align__(16) __hip_bfloat16 sB[64 * 48];
    const int tid = threadIdx.x;
    const int m0 = blockIdx.y * 64;
    const int n0 = blockIdx.x * 64;
    const int w = tid >> 6, lane = tid & 63;
    const int wr = (w >> 1) << 5;
    const int wc = (w & 1) << 5;
    const int lr = lane & 15, lk = lane >> 4;
    const int srow = tid >> 2;
    const int scol = (tid & 3) << 3;
    f32x4 acc[2][2] = {};
    const bool bvalid = (n0 + srow) < N;

    for (int k0 = 0; k0 < K; k0 += 32) {
        uint4 av = {0u, 0u, 0u, 0u}, bv = {0u, 0u, 0u, 0u};
        const bool kv = (k0 + scol) < K;
        if (kv)
            av = *(const uint4*)(A + (size_t)(m0 + srow) * lda + (k0 + scol));
        if (kv && bvalid)
            bv = *(const uint4*)(Bw + (size_t)(n0 + srow) * ldb + (k0 + scol));
        *(uint4*)(sA + srow * 48 + scol) = av;
        *(uint4*)(sB + srow * 48 + scol) = bv;
        __syncthreads();
        short8 af0 = *(const short8*)(sA + (wr + lr) * 48 + (lk << 3));
        short8 af1 = *(const short8*)(sA + (wr + 16 + lr) * 48 + (lk << 3));
        short8 bf0 = *(const short8*)(sB + (wc + lr) * 48 + (lk << 3));
        short8 bf1 = *(const short8*)(sB + (wc + 16 + lr) * 48 + (lk << 3));
        acc[0][0] = __builtin_amdgcn_mfma_f32_16x16x32_bf16(af0, bf0, acc[0][0], 0, 0, 0);
        acc[0][1] = __builtin_amdgcn_mfma_f32_16x16x32_bf16(af0, bf1, acc[0][1], 0, 0, 0);
        acc[1][0] = __builtin_amdgcn_mfma_f32_16x16x32_bf16(af1, bf0, acc[1][0], 0, 0, 0);
        acc[1][1] = __builtin_amdgcn_mfma_f32_16x16x32_bf16(af1, bf1, acc[1][1], 0, 0, 0);
        __syncthreads();
    }
    #pragma unroll
    for (int i = 0; i < 2; ++i) {
        #pragma unroll
        for (int j = 0; j < 2; ++j) {
            const int col = n0 + wc + (j << 4) + lr;
            const int rowb = m0 + wr + (i << 4) + (lk << 2);
            if (col >= N) continue;
            if constexpr (EPI == 0) {
                #pragma unroll
                for (int r = 0; r < 4; ++r)
                    Cf[(size_t)(rowb + r) * ldc + col] = acc[i][j][r];
            } else if constexpr (EPI == 2) {
                f32x4 sp;
                #pragma unroll
                for (int r = 0; r < 4; ++r) {
                    float xx = acc[i][j][r] + bias[col];
                    sp[r] = fmaxf(xx, 0.f) + log1pf(__expf(-fabsf(xx)));
                }
                *(f32x4*)(Cf + (size_t)col * MROWS + rowb) = sp;
            } else if constexpr (EPI == 3) {
                #pragma unroll
                for (int r = 0; r < 4; ++r) {
                    const int row = rowb + r;
                    float v = acc[i][j][r];
                    if (col < RRv)
                        Ch[(size_t)row * RRv + col] = f2bf(v);
                    else if (col < RRv + NSv)
                        Cf[(size_t)row * 128 + 2 * (col - RRv)] = v;
                    else
                        Cf[(size_t)row * 128 + 2 * (col - RRv - NSv) + 1] = v;
                }
            } else {  // EPI == 4
                if (col < DIv) {
                    #pragma unroll
                    for (int r = 0; r < 4; ++r)
                        Ch[(size_t)(rowb + r) * DIv + col] = f2bf(acc[i][j][r]);
                } else {
                    union { ushort4 v; __hip_bfloat16 h[4]; } zz;
                    #pragma unroll
                    for (int r = 0; r < 4; ++r) zz.h[r] = f2bf(acc[i][j][r]);
                    *(ushort4*)(ChT + (size_t)(col - DIv) * MROWS + rowb) = zz.v;
                }
            }
        }
    }
}

// ---------------------------------------------------------------------------
// Causal depthwise conv (DC=4) + bias + SiLU. Reads u buffer [rows, DI].
// ---------------------------------------------------------------------------
__global__ void conv_silu_kernel(const __hip_bfloat16* __restrict__ u_raw,
                                 const float* __restrict__ Wc,
                                 const float* __restrict__ bc,
                                 __hip_bfloat16* __restrict__ uc)
{
    size_t idx = (size_t)blockIdx.x * 256 + threadIdx.x;
    if (idx >= (size_t)MROWS * DIv) return;
    int d = (int)(idx % DIv);
    size_t row = idx / DIv;
    int t = (int)(row % TTv);
    float acc = bc[d];
    #pragma unroll
    for (int k = 0; k < DCv; ++k) {
        int tt = t - (DCv - 1) + k;
        if (tt >= 0)
            acc += Wc[d * DCv + k] *
                   bf2f(u_raw[(row - (DCv - 1) + k) * DIv + d]);
    }
    float s = acc / (1.f + __expf(-acc));
    uc[idx] = f2bf(s);
}

// ---------------------------------------------------------------------------
// Selective scan v3. One wave per (b,d); lane n holds h[n].
// All per-t feeds are t-contiguous (delta_T, uc_T, z_T all [DI, B*T]).
// Partials h*C go to a private LDS slice; every 16 t a transposed reduce +
// fused u*D / silu(z) epilogue writes 16 coalesced y_T outputs.
// ---------------------------------------------------------------------------
__global__ __launch_bounds__(256, 6)
void scan_kernel(const float* __restrict__ deltaT,        // [DI, B*T]
                 const __hip_bfloat16* __restrict__ ucT,  // [DI, B*T]
                 const __hip_bfloat16* __restrict__ zT,   // [DI, B*T]
                 const float* __restrict__ BC,            // [B*T, 128] interleaved
                 const float* __restrict__ a_log,         // [DI, N] layer slice
                 const float* __restrict__ Dp,            // [DI] layer slice
                 __hip_bfloat16* __restrict__ yT)         // [DI, B*T]
{
    __shared__ __align__(16) float vbuf[4 * TBLK * LDST]; // 17408 B
    const int w = threadIdx.x >> 6;
    const int lane = threadIdx.x & 63;
    const int wid = blockIdx.x * 4 + w;
    const int b = __builtin_amdgcn_readfirstlane(wid / DIv);
    const int d = __builtin_amdgcn_readfirstlane(wid % DIv);
    const size_t bT = (size_t)b * TTv;
    const size_t dbase = (size_t)d * MROWS + bT;

    const float A2 = -__expf(a_log[(size_t)d * NSv + lane]) * 1.44269504088896f;
    const float Dd = Dp[d];

    const float* dp = deltaT + dbase;                     // uniform, sequential
    const __hip_bfloat16* up = ucT + dbase;
    const float* bcp = BC + bT * 128 + 2 * lane;
    float* vb = vbuf + w * (TBLK * LDST);

    float2 bc[2][8];
    float  dl[2][8];
    float  uu[2][8];

    #pragma unroll
    for (int i = 0; i < 8; ++i) {
        bc[0][i] = *(const float2*)(bcp + (size_t)i * 128);
        dl[0][i] = dp[i];
        uu[0][i] = bf2f(up[i]);
    }

    float h = 0.f;
    for (int t0 = 0; t0 < TTv; t0 += TBLK) {
        #pragma unroll
        for (int q = 0; q < 2; ++q) {
            const int tn = t0 + q * 8 + 8;
            if (tn < TTv) {
                #pragma unroll
                for (int i = 0; i < 8; ++i) {
                    bc[q ^ 1][i] = *(const float2*)(bcp + (size_t)(tn + i) * 128);
                    dl[q ^ 1][i] = dp[tn + i];
                    uu[q ^ 1][i] = bf2f(up[tn + i]);
                }
            }
            #pragma unroll
            for (int i = 0; i < 8; ++i) {
                const float dlt = dl[q][i];
                const float e = exp2f(dlt * A2);
                h = fmaf(h, e, (dlt * uu[q][i]) * bc[q][i].x);  // carried dep
                vb[(q * 8 + i) * LDST + lane] = h * bc[q][i].y;
            }
        }
        __asm__ volatile("s_waitcnt lgkmcnt(0)" ::: "memory");
        // transposed reduce: lane (r = lane&15, col-group (lane>>4)*16)
        const int r = lane & 15;
        const int cb = (lane >> 4) << 4;
        const float* vr = vb + r * LDST + cb;
        f32x4 a = *(const f32x4*)(vr);
        a += *(const f32x4*)(vr + 4);
        a += *(const f32x4*)(vr + 8);
        a += *(const f32x4*)(vr + 12);
        float s = a[0] + a[1] + a[2] + a[3];
        s += __shfl_xor(s, 16, 64);
        s += __shfl_xor(s, 32, 64);
        if (lane < 16) {
            const size_t g = dbase + t0 + r;
            const float u = bf2f(ucT[g]);
            const float z = bf2f(zT[g]);
            float yv = s + u * Dd;
            yv *= z / (1.f + __expf(-z));                 // * silu(z)
            yT[g] = f2bf(yv);
        }
    }
}

// ---------------------------------------------------------------------------
// LayerNorm + FiLM + residual. One block per (b,t) row of 768.
// ---------------------------------------------------------------------------
__global__ __launch_bounds__(256)
void ln_film_res_kernel(const float* __restrict__ h,
                        const float* __restrict__ xres,
                        const float* __restrict__ lw,
                        const float* __restrict__ lb,
                        const float* __restrict__ gamma,
                        const float* __restrict__ beta,
                        float* __restrict__ xout,
                        __hip_bfloat16* __restrict__ xbf)
{
    __shared__ float sm[4];
    const int row = blockIdx.x;
    const int tid = threadIdx.x;
    const int w = tid >> 6, lane = tid & 63;
    const float* hr = h + (size_t)row * DMv;
    float v0 = hr[tid], v1 = hr[tid + 256], v2 = hr[tid + 512];

    float s = v0 + v1 + v2;
    #pragma unroll
    for (int off = 32; off > 0; off >>= 1) s += __shfl_xor(s, off, 64);
    if (lane == 0) sm[w] = s;
    __syncthreads();
    float mean = (sm[0] + sm[1] + sm[2] + sm[3]) * (1.f / DMv);
    __syncthreads();

    float d0 = v0 - mean, d1 = v1 - mean, d2 = v2 - mean;
    float vs = d0 * d0 + d1 * d1 + d2 * d2;
    #pragma unroll
    for (int off = 32; off > 0; off >>= 1) vs += __shfl_xor(vs, off, 64);
    if (lane == 0) sm[w] = vs;
    __syncthreads();
    float var = (sm[0] + sm[1] + sm[2] + sm[3]) * (1.f / DMv);
    float rstd = rsqrtf(var + 1e-5f);

    const float dv[3] = {d0, d1, d2};
    #pragma unroll
    for (int e = 0; e < 3; ++e) {
        int c = tid + e * 256;
        size_t gi = (size_t)row * DMv + c;
        float ln = dv[e] * rstd * lw[c] + lb[c];
        float f = gamma[gi] * ln + beta[gi];
        float o = f + xres[gi];
        xout[gi] = o;
        xbf[gi] = f2bf(o);
    }
}

// ---------------------------------------------------------------------------
// Launch wrapper
// ---------------------------------------------------------------------------
extern "C" void kernel_launch(void* const* d_in, const int* in_sizes, int n_in,
                              void* d_out, int out_size, void* d_ws, size_t ws_size,
                              hipStream_t stream)
{
    const float* x     = (const float*)d_in[0];
    const float* mask  = (const float*)d_in[1];
    const float* fg    = (const float*)d_in[2];
    const float* fb    = (const float*)d_in[3];
    const float* w_in  = (const float*)d_in[4];
    const float* w_c   = (const float*)d_in[5];
    const float* b_c   = (const float*)d_in[6];
    const float* w_xp  = (const float*)d_in[7];
    const float* w_dt  = (const float*)d_in[8];
    const float* b_dt  = (const float*)d_in[9];
    const float* a_log = (const float*)d_in[10];
    const float* Dp    = (const float*)d_in[11];
    const float* w_out = (const float*)d_in[12];
    const float* ln_w  = (const float*)d_in[13];
    const float* ln_b  = (const float*)d_in[14];

    char* p = (char*)d_ws;
    // u_raw (steps 1-2) then y_T (steps 6-7) — lifetimes disjoint
    __hip_bfloat16* uraw_yT = (__hip_bfloat16*)p; p += (size_t)MROWS * DIv * 2;
    // uc_bf (steps 2-4) then y_bf (steps 7-8) — lifetimes disjoint
    __hip_bfloat16* uc_y    = (__hip_bfloat16*)p; p += (size_t)MROWS * DIv * 2;
    __hip_bfloat16* ucT     = (__hip_bfloat16*)p; p += (size_t)DIv * MROWS * 2;
    __hip_bfloat16* zT      = (__hip_bfloat16*)p; p += (size_t)DIv * MROWS * 2;
    __hip_bfloat16* x_bf    = (__hip_bfloat16*)p; p += (size_t)MROWS * DMv * 2;
    __hip_bfloat16* dtA_bf  = (__hip_bfloat16*)p; p += (size_t)MROWS * RRv * 2;
    __hip_bfloat16* wbf_in  = (__hip_bfloat16*)p; p += (size_t)NLYR * 2 * DIv * DMv * 2;
    __hip_bfloat16* wbf_xp  = (__hip_bfloat16*)p; p += (size_t)NLYR * PJW * DIv * 2;
    __hip_bfloat16* wbf_dt  = (__hip_bfloat16*)p; p += (size_t)NLYR * DIv * RRv * 2;
    __hip_bfloat16* wbf_out = (__hip_bfloat16*)p; p += (size_t)NLYR * DMv * DIv * 2;
    float* BCbuf  = (float*)p; p += (size_t)MROWS * 128 * 4;
    float* deltaT = (float*)p; p += (size_t)DIv * MROWS * 4;
    float* x_cur  = (float*)p; p += (size_t)MROWS * DMv * 4;
    float* hbuf   = deltaT;   // out_proj output aliases deltaT (dead after scan)

    cvt_weights_kernel<<<4096, 256, 0, stream>>>(w_in, w_xp, w_dt, w_out,
                                                 wbf_in, wbf_xp, wbf_dt, wbf_out);
    mask_x_kernel<<<(MROWS * DMv) / 256, 256, 0, stream>>>(x, mask, x_cur, x_bf);

    for (int L = 0; L < NLYR; ++L) {
        const __hip_bfloat16* WinL  = wbf_in  + (size_t)L * 2 * DIv * DMv;
        const __hip_bfloat16* WxpL  = wbf_xp  + (size_t)L * PJW * DIv;
        const __hip_bfloat16* WdtL  = wbf_dt  + (size_t)L * DIv * RRv;
        const __hip_bfloat16* WoutL = wbf_out + (size_t)L * DMv * DIv;

        // 1) in_proj: u -> u_raw [rows,DI], z -> z_T [DI,rows]
        gemm_nt<4><<<dim3(2 * DIv / 64, MROWS / 64), 256, 0, stream>>>(
            x_bf, DMv, WinL, DMv, nullptr, uraw_yT, zT, 0, nullptr,
            MROWS, 2 * DIv, DMv);

        // 2) causal depthwise conv + silu -> uc_bf [rows,DI]
        conv_silu_kernel<<<(MROWS * DIv) / 256, 256, 0, stream>>>(
            uraw_yT, w_c + (size_t)L * DIv * DCv, b_c + (size_t)L * DIv, uc_y);

        // 3) uc_T = transpose(uc_bf)  [DI, rows]
        transpose_bf16<<<dim3(DIv / 64, MROWS / 64), 256, 0, stream>>>(
            (const ushort*)uc_y, (ushort*)ucT, MROWS, DIv);

        // 4) x_proj: dt->bf16 + BC interleaved  (M=8192, N=176, K=1536)
        gemm_nt<3><<<dim3((PJW + 63) / 64, MROWS / 64), 256, 0, stream>>>(
            uc_y, DIv, WxpL, DIv, BCbuf, dtA_bf, nullptr, 0, nullptr,
            MROWS, PJW, DIv);

        // 5) delta_T = softplus(dt @ W_dt^T + b_dt), transposed [DI, rows]
        gemm_nt<2><<<dim3(DIv / 64, MROWS / 64), 256, 0, stream>>>(
            dtA_bf, RRv, WdtL, RRv, deltaT, nullptr, nullptr, 0,
            b_dt + (size_t)L * DIv, MROWS, DIv, RRv);

        // 6) selective scan -> y_T [DI, rows]
        scan_kernel<<<(BBv * DIv) / 4, 256, 0, stream>>>(
            deltaT, ucT, zT, BCbuf,
            a_log + (size_t)L * DIv * NSv, Dp + (size_t)L * DIv, uraw_yT);

        // 7) y = transpose(y_T)  [rows, DI]
        transpose_bf16<<<dim3(MROWS / 64, DIv / 64), 256, 0, stream>>>(
            (const ushort*)uraw_yT, (ushort*)uc_y, DIv, MROWS);

        // 8) h = y @ W_out^T  (M=8192, N=768, K=1536) -> fp32 (aliases deltaT)
        gemm_nt<0><<<dim3(DMv / 64, MROWS / 64), 256, 0, stream>>>(
            uc_y, DIv, WoutL, DIv, hbuf, nullptr, nullptr, DMv, nullptr,
            MROWS, DMv, DIv);

        // 9) LN + FiLM + residual
        float* xo = (L == NLYR - 1) ? (float*)d_out : x_cur;
        ln_film_res_kernel<<<MROWS, 256, 0, stream>>>(
            hbuf, x_cur, ln_w + (size_t)L * DMv, ln_b + (size_t)L * DMv,
            fg + (size_t)L * MROWS * DMv, fb + (size_t)L * MROWS * DMv,
            xo, x_bf);
    }
}

// Round 4
// 1587.760 us; speedup vs baseline: 2.6418x; 1.0456x over previous
//
#include <hip/hip_runtime.h>
#include <hip/hip_bf16.h>
#include <math.h>

// Problem constants
#define BBv   4
#define TTv   2048
#define DMv   768
#define DIv   1536
#define NSv   64
#define DCv   4
#define RRv   48
#define PJW   176              // R + 2N
#define NLYR  2
#define MROWS (BBv * TTv)      // 8192

// Scan tiling
#define TBLK  16               // t-steps per LDS flush
#define LDST  68               // LDS row stride (floats)

typedef __attribute__((ext_vector_type(8))) short short8;
typedef __attribute__((ext_vector_type(4))) float f32x4;

__device__ __forceinline__ __hip_bfloat16 f2bf(float f) { return __float2bfloat16(f); }
__device__ __forceinline__ float bf2f(__hip_bfloat16 h) { return __bfloat162float(h); }
__device__ __forceinline__ float bits2f(unsigned u) {
    union { unsigned u; float f; } c; c.u = u; return c.f;
}

// ---------------------------------------------------------------------------
// Weight conversion fp32 -> bf16
// ---------------------------------------------------------------------------
__global__ void cvt_weights_kernel(const float* __restrict__ w_in,
                                   const float* __restrict__ w_xp,
                                   const float* __restrict__ w_dt,
                                   const float* __restrict__ w_out,
                                   __hip_bfloat16* __restrict__ o_in,
                                   __hip_bfloat16* __restrict__ o_xp,
                                   __hip_bfloat16* __restrict__ o_dt,
                                   __hip_bfloat16* __restrict__ o_out)
{
    const size_t S1 = (size_t)NLYR * 2 * DIv * DMv;
    const size_t S2 = (size_t)NLYR * PJW * DIv;
    const size_t S3 = (size_t)NLYR * DIv * RRv;
    const size_t S4 = (size_t)NLYR * DMv * DIv;
    const size_t total = S1 + S2 + S3 + S4;
    for (size_t i = (size_t)blockIdx.x * blockDim.x + threadIdx.x; i < total;
         i += (size_t)gridDim.x * blockDim.x) {
        if (i < S1)                o_in[i]            = f2bf(w_in[i]);
        else if (i < S1 + S2)      o_xp[i - S1]       = f2bf(w_xp[i - S1]);
        else if (i < S1 + S2 + S3) o_dt[i - S1 - S2]  = f2bf(w_dt[i - S1 - S2]);
        else                       o_out[i - S1 - S2 - S3] = f2bf(w_out[i - S1 - S2 - S3]);
    }
}

// ---------------------------------------------------------------------------
// x_cur = x * mask (fp32) and x_bf = bf16(x_cur)
// ---------------------------------------------------------------------------
__global__ void mask_x_kernel(const float* __restrict__ x,
                              const float* __restrict__ mask,
                              float* __restrict__ x_cur,
                              __hip_bfloat16* __restrict__ x_bf)
{
    size_t idx = (size_t)blockIdx.x * 256 + threadIdx.x;
    if (idx >= (size_t)MROWS * DMv) return;
    size_t row = idx / DMv;
    float v = x[idx] * mask[row];
    x_cur[idx] = v;
    x_bf[idx] = f2bf(v);
}

// ---------------------------------------------------------------------------
// bf16 transpose: in [R, C] -> out [C, R]. 64x64 tiles, 256 threads.
// ---------------------------------------------------------------------------
__global__ __launch_bounds__(256)
void transpose_bf16(const ushort* __restrict__ in, ushort* __restrict__ out,
                    int R, int C)
{
    __shared__ ushort s[64][68];
    const int tx = threadIdx.x & 15;
    const int ty = threadIdx.x >> 4;
    const size_t r0 = (size_t)blockIdx.y * 64;
    const size_t c0 = (size_t)blockIdx.x * 64;
    #pragma unroll
    for (int i = 0; i < 4; ++i) {
        int r = ty + 16 * i;
        ushort4 v = *(const ushort4*)(in + (r0 + r) * C + c0 + tx * 4);
        *(ushort4*)&s[r][tx * 4] = v;
    }
    __syncthreads();
    #pragma unroll
    for (int i = 0; i < 4; ++i) {
        int c = ty + 16 * i;
        ushort4 v;
        v.x = s[tx * 4 + 0][c];
        v.y = s[tx * 4 + 1][c];
        v.z = s[tx * 4 + 2][c];
        v.w = s[tx * 4 + 3][c];
        *(ushort4*)(out + (c0 + c) * R + r0 + tx * 4) = v;
    }
}

// ---------------------------------------------------------------------------
// GEMM: C[m,n] = sum_k A[m,k] * B[n,k]   (A,B bf16)
// EPI 0: fp32 store to Cf[row*ldc+col]
// EPI 2: softplus(x + bias[col]) -> TRANSPOSED fp32 store Cf[col*MROWS+row] (f32x4)
// EPI 3: x_proj split: col<48 -> bf16 dt Ch[row*48+col];
//        col 48..111  -> Cf[row*128 + 2*(col-48)]    (B)
//        col 112..175 -> Cf[row*128 + 2*(col-112)+1] (C)
// EPI 4: in_proj split: col<DI -> bf16 u Ch[row*DI+col];
//        col>=DI -> TRANSPOSED bf16 z ChT[(col-DI)*MROWS+row] (ushort4)
// ---------------------------------------------------------------------------
template<int EPI>
__global__ __launch_bounds__(256)
void gemm_nt(const __hip_bfloat16* __restrict__ A, int lda,
             const __hip_bfloat16* __restrict__ Bw, int ldb,
             float* __restrict__ Cf, __hip_bfloat16* __restrict__ Ch,
             __hip_bfloat16* __restrict__ ChT, int ldc,
             const float* __restrict__ bias, int M, int N, int K)
{
    __shared__ __align__(16) __hip_bfloat16 sA[64 * 48];
    __shared__ __align__(16) __hip_bfloat16 sB[64 * 48];
    const int tid = threadIdx.x;
    const int m0 = blockIdx.y * 64;
    const int n0 = blockIdx.x * 64;
    const int w = tid >> 6, lane = tid & 63;
    const int wr = (w >> 1) << 5;
    const int wc = (w & 1) << 5;
    const int lr = lane & 15, lk = lane >> 4;
    const int srow = tid >> 2;
    const int scol = (tid & 3) << 3;
    f32x4 acc[2][2] = {};
    const bool bvalid = (n0 + srow) < N;

    for (int k0 = 0; k0 < K; k0 += 32) {
        uint4 av = {0u, 0u, 0u, 0u}, bv = {0u, 0u, 0u, 0u};
        const bool kv = (k0 + scol) < K;
        if (kv)
            av = *(const uint4*)(A + (size_t)(m0 + srow) * lda + (k0 + scol));
        if (kv && bvalid)
            bv = *(const uint4*)(Bw + (size_t)(n0 + srow) * ldb + (k0 + scol));
        *(uint4*)(sA + srow * 48 + scol) = av;
        *(uint4*)(sB + srow * 48 + scol) = bv;
        __syncthreads();
        short8 af0 = *(const short8*)(sA + (wr + lr) * 48 + (lk << 3));
        short8 af1 = *(const short8*)(sA + (wr + 16 + lr) * 48 + (lk << 3));
        short8 bf0 = *(const short8*)(sB + (wc + lr) * 48 + (lk << 3));
        short8 bf1 = *(const short8*)(sB + (wc + 16 + lr) * 48 + (lk << 3));
        acc[0][0] = __builtin_amdgcn_mfma_f32_16x16x32_bf16(af0, bf0, acc[0][0], 0, 0, 0);
        acc[0][1] = __builtin_amdgcn_mfma_f32_16x16x32_bf16(af0, bf1, acc[0][1], 0, 0, 0);
        acc[1][0] = __builtin_amdgcn_mfma_f32_16x16x32_bf16(af1, bf0, acc[1][0], 0, 0, 0);
        acc[1][1] = __builtin_amdgcn_mfma_f32_16x16x32_bf16(af1, bf1, acc[1][1], 0, 0, 0);
        __syncthreads();
    }
    #pragma unroll
    for (int i = 0; i < 2; ++i) {
        #pragma unroll
        for (int j = 0; j < 2; ++j) {
            const int col = n0 + wc + (j << 4) + lr;
            const int rowb = m0 + wr + (i << 4) + (lk << 2);
            if (col >= N) continue;
            if constexpr (EPI == 0) {
                #pragma unroll
                for (int r = 0; r < 4; ++r)
                    Cf[(size_t)(rowb + r) * ldc + col] = acc[i][j][r];
            } else if constexpr (EPI == 2) {
                f32x4 sp;
                #pragma unroll
                for (int r = 0; r < 4; ++r) {
                    float xx = acc[i][j][r] + bias[col];
                    sp[r] = fmaxf(xx, 0.f) + log1pf(__expf(-fabsf(xx)));
                }
                *(f32x4*)(Cf + (size_t)col * MROWS + rowb) = sp;
            } else if constexpr (EPI == 3) {
                #pragma unroll
                for (int r = 0; r < 4; ++r) {
                    const int row = rowb + r;
                    float v = acc[i][j][r];
                    if (col < RRv)
                        Ch[(size_t)row * RRv + col] = f2bf(v);
                    else if (col < RRv + NSv)
                        Cf[(size_t)row * 128 + 2 * (col - RRv)] = v;
                    else
                        Cf[(size_t)row * 128 + 2 * (col - RRv - NSv) + 1] = v;
                }
            } else {  // EPI == 4
                if (col < DIv) {
                    #pragma unroll
                    for (int r = 0; r < 4; ++r)
                        Ch[(size_t)(rowb + r) * DIv + col] = f2bf(acc[i][j][r]);
                } else {
                    union { ushort4 v; __hip_bfloat16 h[4]; } zz;
                    #pragma unroll
                    for (int r = 0; r < 4; ++r) zz.h[r] = f2bf(acc[i][j][r]);
                    *(ushort4*)(ChT + (size_t)(col - DIv) * MROWS + rowb) = zz.v;
                }
            }
        }
    }
}

// ---------------------------------------------------------------------------
// Causal depthwise conv (DC=4) + bias + SiLU. Reads u buffer [rows, DI].
// ---------------------------------------------------------------------------
__global__ void conv_silu_kernel(const __hip_bfloat16* __restrict__ u_raw,
                                 const float* __restrict__ Wc,
                                 const float* __restrict__ bc,
                                 __hip_bfloat16* __restrict__ uc)
{
    size_t idx = (size_t)blockIdx.x * 256 + threadIdx.x;
    if (idx >= (size_t)MROWS * DIv) return;
    int d = (int)(idx % DIv);
    size_t row = idx / DIv;
    int t = (int)(row % TTv);
    float acc = bc[d];
    #pragma unroll
    for (int k = 0; k < DCv; ++k) {
        int tt = t - (DCv - 1) + k;
        if (tt >= 0)
            acc += Wc[d * DCv + k] *
                   bf2f(u_raw[(row - (DCv - 1) + k) * DIv + d]);
    }
    float s = acc / (1.f + __expf(-acc));
    uc[idx] = f2bf(s);
}

// ---------------------------------------------------------------------------
// Selective scan v4. One wave per (b,d); lane n holds h[n].
// Vectorized chunk feeds: delta 2x float4 / 8t, u 1x uint4 (8 packed bf16) /
// 8t, BC 8x float2. Unconditional double-buffered prefetch (buffers padded).
// Per-t VALU: unpack + mul(du) + mul+exp(e) + fma(h) + mul(p) + ds_write.
// Every 16 t: transposed LDS reduce + fused u*D / silu(z) epilogue.
// ---------------------------------------------------------------------------
__global__ __launch_bounds__(256, 6)
void scan_kernel(const float* __restrict__ deltaT,        // [DI, B*T] (+pad)
                 const __hip_bfloat16* __restrict__ ucT,  // [DI, B*T] (+pad)
                 const __hip_bfloat16* __restrict__ zT,   // [DI, B*T]
                 const float* __restrict__ BC,            // [B*T, 128] (+pad)
                 const float* __restrict__ a_log,         // [DI, N] layer slice
                 const float* __restrict__ Dp,            // [DI] layer slice
                 __hip_bfloat16* __restrict__ yT)         // [DI, B*T]
{
    __shared__ __align__(16) float vbuf[4 * TBLK * LDST]; // 17408 B
    const int w = threadIdx.x >> 6;
    const int lane = threadIdx.x & 63;
    const int wid = blockIdx.x * 4 + w;
    const int b = __builtin_amdgcn_readfirstlane(wid / DIv);
    const int d = __builtin_amdgcn_readfirstlane(wid % DIv);
    const size_t bT = (size_t)b * TTv;
    const size_t dbase = (size_t)d * MROWS + bT;

    const float A2 = -__expf(a_log[(size_t)d * NSv + lane]) * 1.44269504088896f;
    const float Dd = Dp[d];

    const float4* dp4 = (const float4*)(deltaT + dbase);  // 16B-aligned
    const uint4*  up4 = (const uint4*)(ucT + dbase);      // 8 bf16 / load
    const float*  bcp = BC + bT * 128 + 2 * lane;
    float* vb = vbuf + w * (TBLK * LDST);

    float4 dA[2], dB[2];
    uint4  uu[2];
    float2 bc[2][8];

    // preload chunk 0
    dA[0] = dp4[0]; dB[0] = dp4[1]; uu[0] = up4[0];
    #pragma unroll
    for (int i = 0; i < 8; ++i)
        bc[0][i] = *(const float2*)(bcp + i * 128);

    float h = 0.f;
    for (int t0 = 0; t0 < TTv; t0 += TBLK) {
        #pragma unroll
        for (int q = 0; q < 2; ++q) {
            const int c = (t0 >> 3) + q;
            // prefetch chunk c+1 (unconditional; tail reads land in pad)
            dA[q ^ 1] = dp4[(c + 1) * 2];
            dB[q ^ 1] = dp4[(c + 1) * 2 + 1];
            uu[q ^ 1] = up4[c + 1];
            const float* bq = bcp + (size_t)(c + 1) * 1024;
            #pragma unroll
            for (int i = 0; i < 8; ++i)
                bc[q ^ 1][i] = *(const float2*)(bq + i * 128);

            // unpack current chunk
            float dl[8] = { dA[q].x, dA[q].y, dA[q].z, dA[q].w,
                            dB[q].x, dB[q].y, dB[q].z, dB[q].w };
            float uf[8];
            uf[0] = bits2f(uu[q].x << 16); uf[1] = bits2f(uu[q].x & 0xffff0000u);
            uf[2] = bits2f(uu[q].y << 16); uf[3] = bits2f(uu[q].y & 0xffff0000u);
            uf[4] = bits2f(uu[q].z << 16); uf[5] = bits2f(uu[q].z & 0xffff0000u);
            uf[6] = bits2f(uu[q].w << 16); uf[7] = bits2f(uu[q].w & 0xffff0000u);

            #pragma unroll
            for (int i = 0; i < 8; ++i) {
                const float dlt = dl[i];
                const float e = exp2f(dlt * A2);
                h = fmaf(h, e, (dlt * uf[i]) * bc[q][i].x);  // carried dep
                vb[(q * 8 + i) * LDST + lane] = h * bc[q][i].y;
            }
        }
        __asm__ volatile("s_waitcnt lgkmcnt(0)" ::: "memory");
        // transposed reduce: lane (r = lane&15, col-group (lane>>4)*16)
        const int r = lane & 15;
        const int cb = (lane >> 4) << 4;
        const float* vr = vb + r * LDST + cb;
        f32x4 a = *(const f32x4*)(vr);
        a += *(const f32x4*)(vr + 4);
        a += *(const f32x4*)(vr + 8);
        a += *(const f32x4*)(vr + 12);
        float s = a[0] + a[1] + a[2] + a[3];
        s += __shfl_xor(s, 16, 64);
        s += __shfl_xor(s, 32, 64);
        if (lane < 16) {
            const size_t g = dbase + t0 + r;
            const float u = bf2f(ucT[g]);
            const float z = bf2f(zT[g]);
            float yv = s + u * Dd;
            yv *= z / (1.f + __expf(-z));                 // * silu(z)
            yT[g] = f2bf(yv);
        }
    }
}

// ---------------------------------------------------------------------------
// LayerNorm + FiLM + residual. One block per (b,t) row of 768.
// ---------------------------------------------------------------------------
__global__ __launch_bounds__(256)
void ln_film_res_kernel(const float* __restrict__ h,
                        const float* __restrict__ xres,
                        const float* __restrict__ lw,
                        const float* __restrict__ lb,
                        const float* __restrict__ gamma,
                        const float* __restrict__ beta,
                        float* __restrict__ xout,
                        __hip_bfloat16* __restrict__ xbf)
{
    __shared__ float sm[4];
    const int row = blockIdx.x;
    const int tid = threadIdx.x;
    const int w = tid >> 6, lane = tid & 63;
    const float* hr = h + (size_t)row * DMv;
    float v0 = hr[tid], v1 = hr[tid + 256], v2 = hr[tid + 512];

    float s = v0 + v1 + v2;
    #pragma unroll
    for (int off = 32; off > 0; off >>= 1) s += __shfl_xor(s, off, 64);
    if (lane == 0) sm[w] = s;
    __syncthreads();
    float mean = (sm[0] + sm[1] + sm[2] + sm[3]) * (1.f / DMv);
    __syncthreads();

    float d0 = v0 - mean, d1 = v1 - mean, d2 = v2 - mean;
    float vs = d0 * d0 + d1 * d1 + d2 * d2;
    #pragma unroll
    for (int off = 32; off > 0; off >>= 1) vs += __shfl_xor(vs, off, 64);
    if (lane == 0) sm[w] = vs;
    __syncthreads();
    float var = (sm[0] + sm[1] + sm[2] + sm[3]) * (1.f / DMv);
    float rstd = rsqrtf(var + 1e-5f);

    const float dv[3] = {d0, d1, d2};
    #pragma unroll
    for (int e = 0; e < 3; ++e) {
        int c = tid + e * 256;
        size_t gi = (size_t)row * DMv + c;
        float ln = dv[e] * rstd * lw[c] + lb[c];
        float f = gamma[gi] * ln + beta[gi];
        float o = f + xres[gi];
        xout[gi] = o;
        xbf[gi] = f2bf(o);
    }
}

// ---------------------------------------------------------------------------
// Launch wrapper
// ---------------------------------------------------------------------------
extern "C" void kernel_launch(void* const* d_in, const int* in_sizes, int n_in,
                              void* d_out, int out_size, void* d_ws, size_t ws_size,
                              hipStream_t stream)
{
    const float* x     = (const float*)d_in[0];
    const float* mask  = (const float*)d_in[1];
    const float* fg    = (const float*)d_in[2];
    const float* fb    = (const float*)d_in[3];
    const float* w_in  = (const float*)d_in[4];
    const float* w_c   = (const float*)d_in[5];
    const float* b_c   = (const float*)d_in[6];
    const float* w_xp  = (const float*)d_in[7];
    const float* w_dt  = (const float*)d_in[8];
    const float* b_dt  = (const float*)d_in[9];
    const float* a_log = (const float*)d_in[10];
    const float* Dp    = (const float*)d_in[11];
    const float* w_out = (const float*)d_in[12];
    const float* ln_w  = (const float*)d_in[13];
    const float* ln_b  = (const float*)d_in[14];

    char* p = (char*)d_ws;
    // u_raw (steps 1-2) then y_T (steps 6-7) — lifetimes disjoint
    __hip_bfloat16* uraw_yT = (__hip_bfloat16*)p; p += (size_t)MROWS * DIv * 2;
    // uc_bf (steps 2-4) then y_bf (steps 7-8) — lifetimes disjoint
    __hip_bfloat16* uc_y    = (__hip_bfloat16*)p; p += (size_t)MROWS * DIv * 2;
    __hip_bfloat16* ucT     = (__hip_bfloat16*)p; p += (size_t)DIv * MROWS * 2 + 4096;
    __hip_bfloat16* zT      = (__hip_bfloat16*)p; p += (size_t)DIv * MROWS * 2;
    __hip_bfloat16* x_bf    = (__hip_bfloat16*)p; p += (size_t)MROWS * DMv * 2;
    __hip_bfloat16* dtA_bf  = (__hip_bfloat16*)p; p += (size_t)MROWS * RRv * 2;
    __hip_bfloat16* wbf_in  = (__hip_bfloat16*)p; p += (size_t)NLYR * 2 * DIv * DMv * 2;
    __hip_bfloat16* wbf_xp  = (__hip_bfloat16*)p; p += (size_t)NLYR * PJW * DIv * 2;
    __hip_bfloat16* wbf_dt  = (__hip_bfloat16*)p; p += (size_t)NLYR * DIv * RRv * 2;
    __hip_bfloat16* wbf_out = (__hip_bfloat16*)p; p += (size_t)NLYR * DMv * DIv * 2;
    float* BCbuf  = (float*)p; p += (size_t)MROWS * 128 * 4 + 8192;
    float* deltaT = (float*)p; p += (size_t)DIv * MROWS * 4 + 4096;
    float* x_cur  = (float*)p; p += (size_t)MROWS * DMv * 4;
    float* hbuf   = deltaT;   // out_proj output aliases deltaT (dead after scan)

    cvt_weights_kernel<<<4096, 256, 0, stream>>>(w_in, w_xp, w_dt, w_out,
                                                 wbf_in, wbf_xp, wbf_dt, wbf_out);
    mask_x_kernel<<<(MROWS * DMv) / 256, 256, 0, stream>>>(x, mask, x_cur, x_bf);

    for (int L = 0; L < NLYR; ++L) {
        const __hip_bfloat16* WinL  = wbf_in  + (size_t)L * 2 * DIv * DMv;
        const __hip_bfloat16* WxpL  = wbf_xp  + (size_t)L * PJW * DIv;
        const __hip_bfloat16* WdtL  = wbf_dt  + (size_t)L * DIv * RRv;
        const __hip_bfloat16* WoutL = wbf_out + (size_t)L * DMv * DIv;

        // 1) in_proj: u -> u_raw [rows,DI], z -> z_T [DI,rows]
        gemm_nt<4><<<dim3(2 * DIv / 64, MROWS / 64), 256, 0, stream>>>(
            x_bf, DMv, WinL, DMv, nullptr, uraw_yT, zT, 0, nullptr,
            MROWS, 2 * DIv, DMv);

        // 2) causal depthwise conv + silu -> uc_bf [rows,DI]
        conv_silu_kernel<<<(MROWS * DIv) / 256, 256, 0, stream>>>(
            uraw_yT, w_c + (size_t)L * DIv * DCv, b_c + (size_t)L * DIv, uc_y);

        // 3) uc_T = transpose(uc_bf)  [DI, rows]
        transpose_bf16<<<dim3(DIv / 64, MROWS / 64), 256, 0, stream>>>(
            (const ushort*)uc_y, (ushort*)ucT, MROWS, DIv);

        // 4) x_proj: dt->bf16 + BC interleaved  (M=8192, N=176, K=1536)
        gemm_nt<3><<<dim3((PJW + 63) / 64, MROWS / 64), 256, 0, stream>>>(
            uc_y, DIv, WxpL, DIv, BCbuf, dtA_bf, nullptr, 0, nullptr,
            MROWS, PJW, DIv);

        // 5) delta_T = softplus(dt @ W_dt^T + b_dt), transposed [DI, rows]
        gemm_nt<2><<<dim3(DIv / 64, MROWS / 64), 256, 0, stream>>>(
            dtA_bf, RRv, WdtL, RRv, deltaT, nullptr, nullptr, 0,
            b_dt + (size_t)L * DIv, MROWS, DIv, RRv);

        // 6) selective scan -> y_T [DI, rows]
        scan_kernel<<<(BBv * DIv) / 4, 256, 0, stream>>>(
            deltaT, ucT, zT, BCbuf,
            a_log + (size_t)L * DIv * NSv, Dp + (size_t)L * DIv, uraw_yT);

        // 7) y = transpose(y_T)  [rows, DI]
        transpose_bf16<<<dim3(MROWS / 64, DIv / 64), 256, 0, stream>>>(
            (const ushort*)uraw_yT, (ushort*)uc_y, DIv, MROWS);

        // 8) h = y @ W_out^T  (M=8192, N=768, K=1536) -> fp32 (aliases deltaT)
        gemm_nt<0><<<dim3(DMv / 64, MROWS / 64), 256, 0, stream>>>(
            uc_y, DIv, WoutL, DIv, hbuf, nullptr, nullptr, DMv, nullptr,
            MROWS, DMv, DIv);

        // 9) LN + FiLM + residual
        float* xo = (L == NLYR - 1) ? (float*)d_out : x_cur;
        ln_film_res_kernel<<<MROWS, 256, 0, stream>>>(
            hbuf, x_cur, ln_w + (size_t)L * DMv, ln_b + (size_t)L * DMv,
            fg + (size_t)L * MROWS * DMv, fb + (size_t)L * MROWS * DMv,
            xo, x_bf);
    }
}

// Round 5
// 1553.364 us; speedup vs baseline: 2.7003x; 1.0221x over previous
//
#include <hip/hip_runtime.h>
#include <hip/hip_bf16.h>
#include <math.h>

// Problem constants
#define BBv   4
#define TTv   2048
#define DMv   768
#define DIv   1536
#define NSv   64
#define DCv   4
#define RRv   48
#define PJW   176              // R + 2N
#define NLYR  2
#define MROWS (BBv * TTv)      // 8192

// Scan tiling
#define TBLK  16               // t-steps per LDS flush
#define LDST  68               // LDS row stride (floats)

// GEMM LDS row stride (bf16 elems): 56 -> 112B = 28 banks -> 2-way (free)
#define GST   56

typedef __attribute__((ext_vector_type(8))) short short8;
typedef __attribute__((ext_vector_type(4))) float f32x4;

__device__ __forceinline__ __hip_bfloat16 f2bf(float f) { return __float2bfloat16(f); }
__device__ __forceinline__ float bf2f(__hip_bfloat16 h) { return __bfloat162float(h); }
__device__ __forceinline__ float bits2f(unsigned u) {
    union { unsigned u; float f; } c; c.u = u; return c.f;
}
#define EXP2(x) __builtin_amdgcn_exp2f(x)
#define RCPF(x) __builtin_amdgcn_rcpf(x)
#define LOG2E 1.44269504088896f

// ---------------------------------------------------------------------------
// Weight conversion fp32 -> bf16
// ---------------------------------------------------------------------------
__global__ void cvt_weights_kernel(const float* __restrict__ w_in,
                                   const float* __restrict__ w_xp,
                                   const float* __restrict__ w_dt,
                                   const float* __restrict__ w_out,
                                   __hip_bfloat16* __restrict__ o_in,
                                   __hip_bfloat16* __restrict__ o_xp,
                                   __hip_bfloat16* __restrict__ o_dt,
                                   __hip_bfloat16* __restrict__ o_out)
{
    const size_t S1 = (size_t)NLYR * 2 * DIv * DMv;
    const size_t S2 = (size_t)NLYR * PJW * DIv;
    const size_t S3 = (size_t)NLYR * DIv * RRv;
    const size_t S4 = (size_t)NLYR * DMv * DIv;
    const size_t total = S1 + S2 + S3 + S4;
    for (size_t i = (size_t)blockIdx.x * blockDim.x + threadIdx.x; i < total;
         i += (size_t)gridDim.x * blockDim.x) {
        if (i < S1)                o_in[i]            = f2bf(w_in[i]);
        else if (i < S1 + S2)      o_xp[i - S1]       = f2bf(w_xp[i - S1]);
        else if (i < S1 + S2 + S3) o_dt[i - S1 - S2]  = f2bf(w_dt[i - S1 - S2]);
        else                       o_out[i - S1 - S2 - S3] = f2bf(w_out[i - S1 - S2 - S3]);
    }
}

// ---------------------------------------------------------------------------
// x_cur = x * mask (fp32) and x_bf = bf16(x_cur)
// ---------------------------------------------------------------------------
__global__ void mask_x_kernel(const float* __restrict__ x,
                              const float* __restrict__ mask,
                              float* __restrict__ x_cur,
                              __hip_bfloat16* __restrict__ x_bf)
{
    size_t idx = (size_t)blockIdx.x * 256 + threadIdx.x;
    if (idx >= (size_t)MROWS * DMv) return;
    size_t row = idx / DMv;
    float v = x[idx] * mask[row];
    x_cur[idx] = v;
    x_bf[idx] = f2bf(v);
}

// ---------------------------------------------------------------------------
// bf16 transpose: in [R, C] -> out [C, R]. 64x64 tiles, 256 threads.
// ---------------------------------------------------------------------------
__global__ __launch_bounds__(256)
void transpose_bf16(const ushort* __restrict__ in, ushort* __restrict__ out,
                    int R, int C)
{
    __shared__ ushort s[64][68];
    const int tx = threadIdx.x & 15;
    const int ty = threadIdx.x >> 4;
    const size_t r0 = (size_t)blockIdx.y * 64;
    const size_t c0 = (size_t)blockIdx.x * 64;
    #pragma unroll
    for (int i = 0; i < 4; ++i) {
        int r = ty + 16 * i;
        ushort4 v = *(const ushort4*)(in + (r0 + r) * C + c0 + tx * 4);
        *(ushort4*)&s[r][tx * 4] = v;
    }
    __syncthreads();
    #pragma unroll
    for (int i = 0; i < 4; ++i) {
        int c = ty + 16 * i;
        ushort4 v;
        v.x = s[tx * 4 + 0][c];
        v.y = s[tx * 4 + 1][c];
        v.z = s[tx * 4 + 2][c];
        v.w = s[tx * 4 + 3][c];
        *(ushort4*)(out + (c0 + c) * R + r0 + tx * 4) = v;
    }
}

// ---------------------------------------------------------------------------
// GEMM: C[m,n] = sum_k A[m,k] * B[n,k]   (A,B bf16)
// Tile: 128(M) x 64(N) x 32(K). 256 thr = 4 waves stacked in M (32 rows ea),
// each wave 2x4 MFMAs (16x16x32). LDS row stride 56 elems (2-way banks, free).
// EPI 0: fp32 store to Cf[row*ldc+col]
// EPI 2: softplus(x + bias[col]) -> TRANSPOSED fp32 store Cf[col*MROWS+row]
// EPI 3: x_proj split: col<48 -> bf16 dt Ch[row*48+col];
//        col 48..111  -> Cf[row*128 + 2*(col-48)]    (B)
//        col 112..175 -> Cf[row*128 + 2*(col-112)+1] (C)
// EPI 4: in_proj split: col<DI -> bf16 u Ch[row*DI+col];
//        col>=DI -> TRANSPOSED bf16 z ChT[(col-DI)*MROWS+row] (ushort4)
// ---------------------------------------------------------------------------
template<int EPI>
__global__ __launch_bounds__(256)
void gemm_nt(const __hip_bfloat16* __restrict__ A, int lda,
             const __hip_bfloat16* __restrict__ Bw, int ldb,
             float* __restrict__ Cf, __hip_bfloat16* __restrict__ Ch,
             __hip_bfloat16* __restrict__ ChT, int ldc,
             const float* __restrict__ bias, int M, int N, int K)
{
    __shared__ __align__(16) __hip_bfloat16 sA[128 * GST];  // 14336 B
    __shared__ __align__(16) __hip_bfloat16 sB[64 * GST];   //  7168 B
    const int tid = threadIdx.x;
    const int m0 = blockIdx.y * 128;
    const int n0 = blockIdx.x * 64;
    const int w = tid >> 6, lane = tid & 63;
    const int wr = w << 5;                  // wave's 32-row band
    const int lr = lane & 15, lk = lane >> 4;
    // A staging: thread -> row tid>>1, k-cols (tid&1)*16 .. +16 (two uint4)
    const int ar = tid >> 1;
    const int ak = (tid & 1) << 4;
    // B staging: row tid>>2, k-col (tid&3)*8 (one uint4)
    const int br = tid >> 2;
    const int bk = (tid & 3) << 3;
    f32x4 acc[2][4] = {};
    const bool bvalid = (n0 + br) < N;

    for (int k0 = 0; k0 < K; k0 += 32) {
        uint4 a0 = {0u,0u,0u,0u}, a1 = {0u,0u,0u,0u}, bv = {0u,0u,0u,0u};
        if (k0 + ak < K)
            a0 = *(const uint4*)(A + (size_t)(m0 + ar) * lda + k0 + ak);
        if (k0 + ak + 8 < K)
            a1 = *(const uint4*)(A + (size_t)(m0 + ar) * lda + k0 + ak + 8);
        if (bvalid && k0 + bk < K)
            bv = *(const uint4*)(Bw + (size_t)(n0 + br) * ldb + k0 + bk);
        *(uint4*)(sA + ar * GST + ak) = a0;
        *(uint4*)(sA + ar * GST + ak + 8) = a1;
        *(uint4*)(sB + br * GST + bk) = bv;
        __syncthreads();
        short8 af0 = *(const short8*)(sA + (wr + lr) * GST + (lk << 3));
        short8 af1 = *(const short8*)(sA + (wr + 16 + lr) * GST + (lk << 3));
        short8 bf0 = *(const short8*)(sB + (lr) * GST + (lk << 3));
        short8 bf1 = *(const short8*)(sB + (16 + lr) * GST + (lk << 3));
        short8 bf2 = *(const short8*)(sB + (32 + lr) * GST + (lk << 3));
        short8 bf3 = *(const short8*)(sB + (48 + lr) * GST + (lk << 3));
        acc[0][0] = __builtin_amdgcn_mfma_f32_16x16x32_bf16(af0, bf0, acc[0][0], 0, 0, 0);
        acc[0][1] = __builtin_amdgcn_mfma_f32_16x16x32_bf16(af0, bf1, acc[0][1], 0, 0, 0);
        acc[0][2] = __builtin_amdgcn_mfma_f32_16x16x32_bf16(af0, bf2, acc[0][2], 0, 0, 0);
        acc[0][3] = __builtin_amdgcn_mfma_f32_16x16x32_bf16(af0, bf3, acc[0][3], 0, 0, 0);
        acc[1][0] = __builtin_amdgcn_mfma_f32_16x16x32_bf16(af1, bf0, acc[1][0], 0, 0, 0);
        acc[1][1] = __builtin_amdgcn_mfma_f32_16x16x32_bf16(af1, bf1, acc[1][1], 0, 0, 0);
        acc[1][2] = __builtin_amdgcn_mfma_f32_16x16x32_bf16(af1, bf2, acc[1][2], 0, 0, 0);
        acc[1][3] = __builtin_amdgcn_mfma_f32_16x16x32_bf16(af1, bf3, acc[1][3], 0, 0, 0);
        __syncthreads();
    }
    #pragma unroll
    for (int i = 0; i < 2; ++i) {
        #pragma unroll
        for (int j = 0; j < 4; ++j) {
            const int col = n0 + (j << 4) + lr;
            const int rowb = m0 + wr + (i << 4) + (lk << 2);
            if (col >= N) continue;
            if constexpr (EPI == 0) {
                #pragma unroll
                for (int r = 0; r < 4; ++r)
                    Cf[(size_t)(rowb + r) * ldc + col] = acc[i][j][r];
            } else if constexpr (EPI == 2) {
                f32x4 sp;
                #pragma unroll
                for (int r = 0; r < 4; ++r) {
                    float xx = acc[i][j][r] + bias[col];
                    sp[r] = fmaxf(xx, 0.f) + log1pf(__expf(-fabsf(xx)));
                }
                *(f32x4*)(Cf + (size_t)col * MROWS + rowb) = sp;
            } else if constexpr (EPI == 3) {
                #pragma unroll
                for (int r = 0; r < 4; ++r) {
                    const int row = rowb + r;
                    float v = acc[i][j][r];
                    if (col < RRv)
                        Ch[(size_t)row * RRv + col] = f2bf(v);
                    else if (col < RRv + NSv)
                        Cf[(size_t)row * 128 + 2 * (col - RRv)] = v;
                    else
                        Cf[(size_t)row * 128 + 2 * (col - RRv - NSv) + 1] = v;
                }
            } else {  // EPI == 4
                if (col < DIv) {
                    #pragma unroll
                    for (int r = 0; r < 4; ++r)
                        Ch[(size_t)(rowb + r) * DIv + col] = f2bf(acc[i][j][r]);
                } else {
                    union { ushort4 v; __hip_bfloat16 h[4]; } zz;
                    #pragma unroll
                    for (int r = 0; r < 4; ++r) zz.h[r] = f2bf(acc[i][j][r]);
                    *(ushort4*)(ChT + (size_t)(col - DIv) * MROWS + rowb) = zz.v;
                }
            }
        }
    }
}

// ---------------------------------------------------------------------------
// Causal depthwise conv (DC=4) + bias + SiLU. Reads u buffer [rows, DI].
// ---------------------------------------------------------------------------
__global__ void conv_silu_kernel(const __hip_bfloat16* __restrict__ u_raw,
                                 const float* __restrict__ Wc,
                                 const float* __restrict__ bc,
                                 __hip_bfloat16* __restrict__ uc)
{
    size_t idx = (size_t)blockIdx.x * 256 + threadIdx.x;
    if (idx >= (size_t)MROWS * DIv) return;
    int d = (int)(idx % DIv);
    size_t row = idx / DIv;
    int t = (int)(row % TTv);
    float acc = bc[d];
    #pragma unroll
    for (int k = 0; k < DCv; ++k) {
        int tt = t - (DCv - 1) + k;
        if (tt >= 0)
            acc += Wc[d * DCv + k] *
                   bf2f(u_raw[(row - (DCv - 1) + k) * DIv + d]);
    }
    float s = acc * RCPF(1.f + EXP2(-acc * LOG2E));
    uc[idx] = f2bf(s);
}

// ---------------------------------------------------------------------------
// Selective scan v5. One wave per (b,d); lane n holds h[n].
// Same structure as v4 but raw-HW exponentials (__builtin_amdgcn_exp2f) and
// rcp-based sigmoid: per-t path is mul, v_exp, mul, mul, fmac, mul, ds_write.
// ---------------------------------------------------------------------------
__global__ __launch_bounds__(256, 6)
void scan_kernel(const float* __restrict__ deltaT,        // [DI, B*T] (+pad)
                 const __hip_bfloat16* __restrict__ ucT,  // [DI, B*T] (+pad)
                 const __hip_bfloat16* __restrict__ zT,   // [DI, B*T]
                 const float* __restrict__ BC,            // [B*T, 128] (+pad)
                 const float* __restrict__ a_log,         // [DI, N] layer slice
                 const float* __restrict__ Dp,            // [DI] layer slice
                 __hip_bfloat16* __restrict__ yT)         // [DI, B*T]
{
    __shared__ __align__(16) float vbuf[4 * TBLK * LDST]; // 17408 B
    const int w = threadIdx.x >> 6;
    const int lane = threadIdx.x & 63;
    const int wid = blockIdx.x * 4 + w;
    const int b = __builtin_amdgcn_readfirstlane(wid / DIv);
    const int d = __builtin_amdgcn_readfirstlane(wid % DIv);
    const size_t bT = (size_t)b * TTv;
    const size_t dbase = (size_t)d * MROWS + bT;

    // A2 = -exp(a_log) * log2(e) via HW exp2: exp(a) = exp2(a*log2e)
    const float A2 = -EXP2(a_log[(size_t)d * NSv + lane] * LOG2E) * LOG2E;
    const float Dd = Dp[d];

    const float4* dp4 = (const float4*)(deltaT + dbase);  // wave-uniform
    const uint4*  up4 = (const uint4*)(ucT + dbase);      // 8 bf16 / load
    const float*  bcp = BC + bT * 128 + 2 * lane;
    float* vb = vbuf + w * (TBLK * LDST);

    float4 dA[2], dB[2];
    uint4  uu[2];
    float2 bc[2][8];

    // preload chunk 0
    dA[0] = dp4[0]; dB[0] = dp4[1]; uu[0] = up4[0];
    #pragma unroll
    for (int i = 0; i < 8; ++i)
        bc[0][i] = *(const float2*)(bcp + i * 128);

    float h = 0.f;
    for (int t0 = 0; t0 < TTv; t0 += TBLK) {
        #pragma unroll
        for (int q = 0; q < 2; ++q) {
            const int c = (t0 >> 3) + q;
            // prefetch chunk c+1 (unconditional; tail reads land in pad)
            dA[q ^ 1] = dp4[(c + 1) * 2];
            dB[q ^ 1] = dp4[(c + 1) * 2 + 1];
            uu[q ^ 1] = up4[c + 1];
            const float* bq = bcp + (size_t)(c + 1) * 1024;
            #pragma unroll
            for (int i = 0; i < 8; ++i)
                bc[q ^ 1][i] = *(const float2*)(bq + i * 128);

            // unpack current chunk
            float dl[8] = { dA[q].x, dA[q].y, dA[q].z, dA[q].w,
                            dB[q].x, dB[q].y, dB[q].z, dB[q].w };
            float uf[8];
            uf[0] = bits2f(uu[q].x << 16); uf[1] = bits2f(uu[q].x & 0xffff0000u);
            uf[2] = bits2f(uu[q].y << 16); uf[3] = bits2f(uu[q].y & 0xffff0000u);
            uf[4] = bits2f(uu[q].z << 16); uf[5] = bits2f(uu[q].z & 0xffff0000u);
            uf[6] = bits2f(uu[q].w << 16); uf[7] = bits2f(uu[q].w & 0xffff0000u);

            #pragma unroll
            for (int i = 0; i < 8; ++i) {
                const float dlt = dl[i];
                const float e = EXP2(dlt * A2);              // raw v_exp_f32
                h = fmaf(h, e, (dlt * uf[i]) * bc[q][i].x);  // carried dep
                vb[(q * 8 + i) * LDST + lane] = h * bc[q][i].y;
            }
        }
        __asm__ volatile("s_waitcnt lgkmcnt(0)" ::: "memory");
        // transposed reduce: lane (r = lane&15, col-group (lane>>4)*16)
        const int r = lane & 15;
        const int cb = (lane >> 4) << 4;
        const float* vr = vb + r * LDST + cb;
        f32x4 a = *(const f32x4*)(vr);
        a += *(const f32x4*)(vr + 4);
        a += *(const f32x4*)(vr + 8);
        a += *(const f32x4*)(vr + 12);
        float s = a[0] + a[1] + a[2] + a[3];
        s += __shfl_xor(s, 16, 64);
        s += __shfl_xor(s, 32, 64);
        if (lane < 16) {
            const size_t g = dbase + t0 + r;
            const float u = bf2f(ucT[g]);
            const float z = bf2f(zT[g]);
            float yv = s + u * Dd;
            yv *= z * RCPF(1.f + EXP2(-z * LOG2E));          // * silu(z)
            yT[g] = f2bf(yv);
        }
    }
}

// ---------------------------------------------------------------------------
// LayerNorm + FiLM + residual. One block per (b,t) row of 768.
// ---------------------------------------------------------------------------
__global__ __launch_bounds__(256)
void ln_film_res_kernel(const float* __restrict__ h,
                        const float* __restrict__ xres,
                        const float* __restrict__ lw,
                        const float* __restrict__ lb,
                        const float* __restrict__ gamma,
                        const float* __restrict__ beta,
                        float* __restrict__ xout,
                        __hip_bfloat16* __restrict__ xbf)
{
    __shared__ float sm[4];
    const int row = blockIdx.x;
    const int tid = threadIdx.x;
    const int w = tid >> 6, lane = tid & 63;
    const float* hr = h + (size_t)row * DMv;
    float v0 = hr[tid], v1 = hr[tid + 256], v2 = hr[tid + 512];

    float s = v0 + v1 + v2;
    #pragma unroll
    for (int off = 32; off > 0; off >>= 1) s += __shfl_xor(s, off, 64);
    if (lane == 0) sm[w] = s;
    __syncthreads();
    float mean = (sm[0] + sm[1] + sm[2] + sm[3]) * (1.f / DMv);
    __syncthreads();

    float d0 = v0 - mean, d1 = v1 - mean, d2 = v2 - mean;
    float vs = d0 * d0 + d1 * d1 + d2 * d2;
    #pragma unroll
    for (int off = 32; off > 0; off >>= 1) vs += __shfl_xor(vs, off, 64);
    if (lane == 0) sm[w] = vs;
    __syncthreads();
    float var = (sm[0] + sm[1] + sm[2] + sm[3]) * (1.f / DMv);
    float rstd = rsqrtf(var + 1e-5f);

    const float dv[3] = {d0, d1, d2};
    #pragma unroll
    for (int e = 0; e < 3; ++e) {
        int c = tid + e * 256;
        size_t gi = (size_t)row * DMv + c;
        float ln = dv[e] * rstd * lw[c] + lb[c];
        float f = gamma[gi] * ln + beta[gi];
        float o = f + xres[gi];
        xout[gi] = o;
        xbf[gi] = f2bf(o);
    }
}

// ---------------------------------------------------------------------------
// Launch wrapper
// ---------------------------------------------------------------------------
extern "C" void kernel_launch(void* const* d_in, const int* in_sizes, int n_in,
                              void* d_out, int out_size, void* d_ws, size_t ws_size,
                              hipStream_t stream)
{
    const float* x     = (const float*)d_in[0];
    const float* mask  = (const float*)d_in[1];
    const float* fg    = (const float*)d_in[2];
    const float* fb    = (const float*)d_in[3];
    const float* w_in  = (const float*)d_in[4];
    const float* w_c   = (const float*)d_in[5];
    const float* b_c   = (const float*)d_in[6];
    const float* w_xp  = (const float*)d_in[7];
    const float* w_dt  = (const float*)d_in[8];
    const float* b_dt  = (const float*)d_in[9];
    const float* a_log = (const float*)d_in[10];
    const float* Dp    = (const float*)d_in[11];
    const float* w_out = (const float*)d_in[12];
    const float* ln_w  = (const float*)d_in[13];
    const float* ln_b  = (const float*)d_in[14];

    char* p = (char*)d_ws;
    // u_raw (steps 1-2) then y_T (steps 6-7) — lifetimes disjoint
    __hip_bfloat16* uraw_yT = (__hip_bfloat16*)p; p += (size_t)MROWS * DIv * 2;
    // uc_bf (steps 2-4) then y_bf (steps 7-8) — lifetimes disjoint
    __hip_bfloat16* uc_y    = (__hip_bfloat16*)p; p += (size_t)MROWS * DIv * 2;
    __hip_bfloat16* ucT     = (__hip_bfloat16*)p; p += (size_t)DIv * MROWS * 2 + 4096;
    __hip_bfloat16* zT      = (__hip_bfloat16*)p; p += (size_t)DIv * MROWS * 2;
    __hip_bfloat16* x_bf    = (__hip_bfloat16*)p; p += (size_t)MROWS * DMv * 2;
    __hip_bfloat16* dtA_bf  = (__hip_bfloat16*)p; p += (size_t)MROWS * RRv * 2;
    __hip_bfloat16* wbf_in  = (__hip_bfloat16*)p; p += (size_t)NLYR * 2 * DIv * DMv * 2;
    __hip_bfloat16* wbf_xp  = (__hip_bfloat16*)p; p += (size_t)NLYR * PJW * DIv * 2;
    __hip_bfloat16* wbf_dt  = (__hip_bfloat16*)p; p += (size_t)NLYR * DIv * RRv * 2;
    __hip_bfloat16* wbf_out = (__hip_bfloat16*)p; p += (size_t)NLYR * DMv * DIv * 2;
    float* BCbuf  = (float*)p; p += (size_t)MROWS * 128 * 4 + 8192;
    float* deltaT = (float*)p; p += (size_t)DIv * MROWS * 4 + 4096;
    float* x_cur  = (float*)p; p += (size_t)MROWS * DMv * 4;
    float* hbuf   = deltaT;   // out_proj output aliases deltaT (dead after scan)

    cvt_weights_kernel<<<4096, 256, 0, stream>>>(w_in, w_xp, w_dt, w_out,
                                                 wbf_in, wbf_xp, wbf_dt, wbf_out);
    mask_x_kernel<<<(MROWS * DMv) / 256, 256, 0, stream>>>(x, mask, x_cur, x_bf);

    for (int L = 0; L < NLYR; ++L) {
        const __hip_bfloat16* WinL  = wbf_in  + (size_t)L * 2 * DIv * DMv;
        const __hip_bfloat16* WxpL  = wbf_xp  + (size_t)L * PJW * DIv;
        const __hip_bfloat16* WdtL  = wbf_dt  + (size_t)L * DIv * RRv;
        const __hip_bfloat16* WoutL = wbf_out + (size_t)L * DMv * DIv;

        // 1) in_proj: u -> u_raw [rows,DI], z -> z_T [DI,rows]
        gemm_nt<4><<<dim3(2 * DIv / 64, MROWS / 128), 256, 0, stream>>>(
            x_bf, DMv, WinL, DMv, nullptr, uraw_yT, zT, 0, nullptr,
            MROWS, 2 * DIv, DMv);

        // 2) causal depthwise conv + silu -> uc_bf [rows,DI]
        conv_silu_kernel<<<(MROWS * DIv) / 256, 256, 0, stream>>>(
            uraw_yT, w_c + (size_t)L * DIv * DCv, b_c + (size_t)L * DIv, uc_y);

        // 3) uc_T = transpose(uc_bf)  [DI, rows]
        transpose_bf16<<<dim3(DIv / 64, MROWS / 64), 256, 0, stream>>>(
            (const ushort*)uc_y, (ushort*)ucT, MROWS, DIv);

        // 4) x_proj: dt->bf16 + BC interleaved  (M=8192, N=176, K=1536)
        gemm_nt<3><<<dim3((PJW + 63) / 64, MROWS / 128), 256, 0, stream>>>(
            uc_y, DIv, WxpL, DIv, BCbuf, dtA_bf, nullptr, 0, nullptr,
            MROWS, PJW, DIv);

        // 5) delta_T = softplus(dt @ W_dt^T + b_dt), transposed [DI, rows]
        gemm_nt<2><<<dim3(DIv / 64, MROWS / 128), 256, 0, stream>>>(
            dtA_bf, RRv, WdtL, RRv, deltaT, nullptr, nullptr, 0,
            b_dt + (size_t)L * DIv, MROWS, DIv, RRv);

        // 6) selective scan -> y_T [DI, rows]
        scan_kernel<<<(BBv * DIv) / 4, 256, 0, stream>>>(
            deltaT, ucT, zT, BCbuf,
            a_log + (size_t)L * DIv * NSv, Dp + (size_t)L * DIv, uraw_yT);

        // 7) y = transpose(y_T)  [rows, DI]
        transpose_bf16<<<dim3(MROWS / 64, DIv / 64), 256, 0, stream>>>(
            (const ushort*)uraw_yT, (ushort*)uc_y, DIv, MROWS);

        // 8) h = y @ W_out^T  (M=8192, N=768, K=1536) -> fp32 (aliases deltaT)
        gemm_nt<0><<<dim3(DMv / 64, MROWS / 128), 256, 0, stream>>>(
            uc_y, DIv, WoutL, DIv, hbuf, nullptr, nullptr, DMv, nullptr,
            MROWS, DMv, DIv);

        // 9) LN + FiLM + residual
        float* xo = (L == NLYR - 1) ? (float*)d_out : x_cur;
        ln_film_res_kernel<<<MROWS, 256, 0, stream>>>(
            hbuf, x_cur, ln_w + (size_t)L * DMv, ln_b + (size_t)L * DMv,
            fg + (size_t)L * MROWS * DMv, fb + (size_t)L * MROWS * DMv,
            xo, x_bf);
    }
}